// Round 7
// baseline (324.723 us; speedup 1.0000x reference)
//
#include <hip/hip_runtime.h>

typedef unsigned short u16;
typedef __attribute__((ext_vector_type(8))) short s8v;
typedef __attribute__((ext_vector_type(4))) float f4v;

enum { MODE_PLAIN = 0, MODE_SCALE = 2, MODE_FINAL = 3, MODE_PV = 4 };

__device__ __forceinline__ u16 f2bf(float f) {
  unsigned u = __builtin_bit_cast(unsigned, f);
  u += 0x7fffu + ((u >> 16) & 1u);
  return (u16)(u >> 16);
}
__device__ __forceinline__ float bf2f(u16 h) {
  unsigned u = ((unsigned)h) << 16;
  return __builtin_bit_cast(float, u);
}
__device__ __forceinline__ void gload16(const void* g, void* l) {
  __builtin_amdgcn_global_load_lds(
      (const __attribute__((address_space(1))) unsigned int*)g,
      (__attribute__((address_space(3))) unsigned int*)l, 16, 0, 0);
}

// ---------------- weight fp32 -> bf16 ----------------
__global__ __launch_bounds__(256) void w2bf(const float* __restrict__ w0,
                                            const float* __restrict__ w1,
                                            const float* __restrict__ w2,
                                            const float* __restrict__ w3,
                                            u16* __restrict__ out) {
  int which = blockIdx.y;
  const float* w = which == 0 ? w0 : which == 1 ? w1 : which == 2 ? w2 : w3;
  int i = (blockIdx.x * 256 + threadIdx.x) * 4;
  float4 f = *(const float4*)(w + i);
  u16* o = out + (long)which * 262144 + i;
  ushort4 r;
  r.x = f2bf(f.x); r.y = f2bf(f.y); r.z = f2bf(f.z); r.w = f2bf(f.w);
  *(ushort4*)o = r;
}

// ---------------- groupnorm: partial stats ----------------
__global__ __launch_bounds__(256) void gn_stats(const float* __restrict__ x,
                                                float2* __restrict__ part) {
  const int bid = blockIdx.x;
  const float4* p4 = (const float4*)(x + (long)bid * 8192);
  float s = 0.f, q = 0.f;
  int t = threadIdx.x;
#pragma unroll
  for (int j = 0; j < 8; ++j) {
    float4 f = p4[t + 256 * j];
    s += f.x + f.y + f.z + f.w;
    q += f.x * f.x + f.y * f.y + f.z * f.z + f.w * f.w;
  }
#pragma unroll
  for (int o = 32; o; o >>= 1) {
    s += __shfl_xor(s, o, 64);
    q += __shfl_xor(q, o, 64);
  }
  __shared__ float rs[4], rq[4];
  int lane = t & 63, wv = t >> 6;
  if (lane == 0) { rs[wv] = s; rq[wv] = q; }
  __syncthreads();
  if (t == 0)
    part[bid] = make_float2(rs[0] + rs[1] + rs[2] + rs[3],
                            rq[0] + rq[1] + rq[2] + rq[3]);
}

// ---------------- groupnorm: per-channel scale/shift ----------------
__global__ __launch_bounds__(256) void gn_ab(const float2* __restrict__ part,
                                             const float* __restrict__ gamma,
                                             const float* __restrict__ beta,
                                             float2* __restrict__ AB) {
  int idx = blockIdx.x * 256 + threadIdx.x;
  int g = idx >> 4;
  float s = 0.f, q = 0.f;
#pragma unroll
  for (int j = 0; j < 8; ++j) {
    float2 pp = part[g * 8 + j];
    s += pp.x; q += pp.y;
  }
  float mean = s * (1.0f / 65536.0f);
  float var = q * (1.0f / 65536.0f) - mean * mean;
  int c = idx & 511;
  float a = gamma[c] * rsqrtf(var + 1e-6f);
  AB[idx] = make_float2(a, beta[c] - mean * a);
}

// ---------------- apply groupnorm + transpose ----------------
__global__ __launch_bounds__(256) void gn_apply_t(const float* __restrict__ x,
                                                  const float2* __restrict__ AB,
                                                  u16* __restrict__ hnt) {
  int p0 = blockIdx.x * 32, c0 = blockIdx.y * 32, b = blockIdx.z;
  __shared__ float tile[32][33];
  int t = threadIdx.x;
  const float* xb = x + (long)b * 2097152;
#pragma unroll
  for (int j = 0; j < 4; ++j) {
    int lc = (t >> 5) + j * 8, lp = t & 31;
    tile[lc][lp] = xb[(long)(c0 + lc) * 4096 + p0 + lp];
  }
  __syncthreads();
#pragma unroll
  for (int j = 0; j < 4; ++j) {
    int lp = (t >> 5) + j * 8, lc = t & 31;
    float2 ab = AB[b * 512 + c0 + lc];
    float val = tile[lc][lp] * ab.x + ab.y;
    hnt[(long)b * 2097152 + (long)(p0 + lp) * 512 + c0 + lc] = f2bf(val);
  }
}

// ---------------- in-place row softmax on bf16 [8192][4096] ----------------
__global__ __launch_bounds__(256) void softmax_rows(u16* __restrict__ S) {
  u16* p = S + (long)blockIdx.x * 4096;
  const int t = threadIdx.x;
  s8v h0 = ((const s8v*)p)[t * 2];
  s8v h1 = ((const s8v*)p)[t * 2 + 1];
  float v[16];
#pragma unroll
  for (int j = 0; j < 8; ++j) {
    v[j] = bf2f((u16)h0[j]);
    v[8 + j] = bf2f((u16)h1[j]);
  }
  float mx = v[0];
#pragma unroll
  for (int j = 1; j < 16; ++j) mx = fmaxf(mx, v[j]);
#pragma unroll
  for (int o = 32; o; o >>= 1) mx = fmaxf(mx, __shfl_xor(mx, o, 64));
  __shared__ float red[4], red2[4];
  int lane = t & 63, wv = t >> 6;
  if (lane == 0) red[wv] = mx;
  __syncthreads();
  mx = fmaxf(fmaxf(red[0], red[1]), fmaxf(red[2], red[3]));
  float s = 0.f;
#pragma unroll
  for (int j = 0; j < 16; ++j) {
    v[j] = __expf(v[j] - mx);
    s += v[j];
  }
#pragma unroll
  for (int o = 32; o; o >>= 1) s += __shfl_xor(s, o, 64);
  if (lane == 0) red2[wv] = s;
  __syncthreads();
  s = red2[0] + red2[1] + red2[2] + red2[3];
  float inv = 1.0f / s;
  s8v o0, o1;
#pragma unroll
  for (int j = 0; j < 8; ++j) {
    o0[j] = (short)f2bf(v[j] * inv);
    o1[j] = (short)f2bf(v[8 + j] * inv);
  }
  ((s8v*)p)[t * 2] = o0;
  ((s8v*)p)[t * 2 + 1] = o1;
}

// ---------------- split-K reduce: out = p[i] + p[4194304+i] (bf16) ---------
__global__ __launch_bounds__(256) void reduce_pv(const u16* __restrict__ p,
                                                 u16* __restrict__ out) {
  long i = ((long)blockIdx.x * 256 + threadIdx.x) * 8;
  s8v a = *(const s8v*)(p + i);
  s8v b = *(const s8v*)(p + 4194304 + i);
  s8v o;
#pragma unroll
  for (int j = 0; j < 8; ++j)
    o[j] = (short)f2bf(bf2f((u16)a[j]) + bf2f((u16)b[j]));
  *(s8v*)(out + i) = o;
}

// ---------------- fused QKV GEMM (unchanged from r6) ----------------------
__global__ __launch_bounds__(256) void gemm_qkv3(
    const u16* __restrict__ hnt, const u16* __restrict__ wqb,
    u16* __restrict__ qt, u16* __restrict__ kt, u16* __restrict__ vt,
    const float* __restrict__ bq, const float* __restrict__ bk,
    const float* __restrict__ bv) {
  constexpr int MI = 4, NI = 2, AGW = 2, NLD = 5;
  __shared__ __align__(16) u16 la[3][4096];
  __shared__ __align__(16) u16 lb[3][3][2048];
  const int t = threadIdx.x;
  const int lane = t & 63, wv = t >> 6;
  const int wm = wv >> 1, wn = wv & 1;

  int lin = blockIdx.x;
  int xcd = lin & 7, s = lin >> 3;
  int bn_i = s % 8, t2 = s / 8;
  int bm_i = (t2 % 4) * 8 + xcd;
  int bb = t2 / 4;
  const int bm = bm_i * 128, bn = bn_i * 64;

  const u16* A = hnt + (long)bb * 2097152;
  const u16* aP[AGW];
#pragma unroll
  for (int j = 0; j < AGW; ++j)
    aP[j] = A + (long)(bm + (wv + j * 4) * 16 + (lane & 15)) * 512 +
            (lane >> 4) * 8;
  const u16* bP[3];
#pragma unroll
  for (int w = 0; w < 3; ++w)
    bP[w] = wqb + (long)w * 262144 +
            (long)(bn + wv * 16 + (lane & 15)) * 512 + (lane >> 4) * 8;

  auto issue = [&](int buf) {
#pragma unroll
    for (int j = 0; j < AGW; ++j) {
      gload16(aP[j], &la[buf][(wv + j * 4) * 512 + lane * 8]);
      aP[j] += 32;
    }
#pragma unroll
    for (int w = 0; w < 3; ++w) {
      gload16(bP[w], &lb[buf][w][wv * 512 + lane * 8]);
      bP[w] += 32;
    }
  };

  f4v acc[3][MI][NI];
#pragma unroll
  for (int w = 0; w < 3; ++w)
#pragma unroll
    for (int i = 0; i < MI; ++i)
#pragma unroll
      for (int j = 0; j < NI; ++j) acc[w][i][j] = (f4v){0.f, 0.f, 0.f, 0.f};

  issue(0);
  issue(1);
  int cur = 0, nxt = 2;
  for (int it = 0; it < 16; ++it) {
    if (it < 15)
      asm volatile("s_waitcnt vmcnt(%0)" ::"n"(NLD) : "memory");
    else
      asm volatile("s_waitcnt vmcnt(0)" ::: "memory");
    asm volatile("s_barrier" ::: "memory");
    if (it + 2 < 16) issue(nxt);

    s8v af[MI], bfr[3][NI];
#pragma unroll
    for (int mi = 0; mi < MI; ++mi)
      af[mi] = *(const s8v*)&la[cur][((wm * MI + mi) * 64 + lane) * 8];
#pragma unroll
    for (int w = 0; w < 3; ++w)
#pragma unroll
      for (int ni = 0; ni < NI; ++ni)
        bfr[w][ni] =
            *(const s8v*)&lb[cur][w][((wn * NI + ni) * 64 + lane) * 8];
#pragma unroll
    for (int w = 0; w < 3; ++w)
#pragma unroll
      for (int mi = 0; mi < MI; ++mi)
#pragma unroll
        for (int ni = 0; ni < NI; ++ni)
          acc[w][mi][ni] = __builtin_amdgcn_mfma_f32_16x16x32_bf16(
              af[mi], bfr[w][ni], acc[w][mi][ni], 0, 0, 0);
    cur = cur == 2 ? 0 : cur + 1;
    nxt = nxt == 2 ? 0 : nxt + 1;
  }

  const int quad = lane >> 4, col = lane & 15;
#pragma unroll
  for (int w = 0; w < 3; ++w) {
    const float* bias = w == 0 ? bq : w == 1 ? bk : bv;
    u16* dst = w == 0 ? qt : kt;
#pragma unroll
    for (int mi = 0; mi < MI; ++mi) {
#pragma unroll
      for (int ni = 0; ni < NI; ++ni) {
        int n = bn + wn * 32 + ni * 16 + col;
        int m0 = bm + wm * 64 + mi * 16 + quad * 4;
        f4v vv = acc[w][mi][ni];
        float bsv = bias[n];
        if (w == 2) {
          ushort4 pk;
          pk.x = f2bf(vv[0] + bsv); pk.y = f2bf(vv[1] + bsv);
          pk.z = f2bf(vv[2] + bsv); pk.w = f2bf(vv[3] + bsv);
          *(ushort4*)&vt[(long)bb * 2097152 + (long)n * 4096 + m0] = pk;
        } else {
#pragma unroll
          for (int r2 = 0; r2 < 4; ++r2)
            dst[(long)bb * 2097152 + (long)(m0 + r2) * 512 + n] =
                f2bf(vv[r2] + bsv);
        }
      }
    }
  }
}

// ---------------- NT GEMM: C[M][N] = A[M][K] * Bt[N][K]^T ----------------
// Asymmetric pipeline: A 2-stage (1-iter lookahead; A panels are L2-hot —
// co-resident blocks on an XCD share bm), B 3-stage (2-iter lookahead for
// IC-latency panels). One s_barrier per K-step; vmcnt never 0 mid-loop.
// FIFO per iter: issue A(it+1) then B(it+2); steady wait = vmcnt(BGW).
template <int MODE, int BM, int BN>
__global__ __launch_bounds__(256) void gemm_nt(
    const u16* __restrict__ Ag, long sA, const u16* __restrict__ Btg, long sB,
    void* __restrict__ Cg, long sC, int nx, int nyg, int K, long lda, long ldb,
    int N, const float* __restrict__ b0, const float* __restrict__ resid,
    long sR, float scale) {
  constexpr int MI = BM / 32, NI = BN / 32;
  constexpr int AGW = BM / 64, BGW = BN / 64;
  __shared__ __align__(16) u16 lds_a[2][BM * 32];
  __shared__ __align__(16) u16 lds_b[3][BN * 32];
  const int t = threadIdx.x;
  const int lane = t & 63, wv = t >> 6;
  const int wm = wv >> 1, wn = wv & 1;

  int lin = blockIdx.x;
  int xcd = lin & 7, s = lin >> 3;
  int bn_i = s % nx, t2 = s / nx;
  int bm_i = (t2 % nyg) * 8 + xcd;
  int bz = t2 / nyg;

  const u16* A = Ag;
  const u16* Bt = Btg;
  long c_off = 0;
  if constexpr (MODE == MODE_PV) {
    int ks = bz >> 1, bb = bz & 1;
    A += (long)bb * sA + (long)ks * 2048;
    Bt += (long)bb * sB + (long)ks * 2048;
    c_off = (long)ks * 4194304 + (long)bb * sC;
  } else {
    A += (long)bz * sA;
    Bt += (long)bz * sB;
    c_off = (long)bz * sC;
  }
  const int bm = bm_i * BM, bn = bn_i * BN;

  const u16* aP[AGW];
  const u16* bP[BGW];
#pragma unroll
  for (int j = 0; j < AGW; ++j)
    aP[j] = A + (long)(bm + (wv + j * 4) * 16 + (lane & 15)) * lda +
            (lane >> 4) * 8;
#pragma unroll
  for (int j = 0; j < BGW; ++j)
    bP[j] = Bt + (long)(bn + (wv + j * 4) * 16 + (lane & 15)) * ldb +
            (lane >> 4) * 8;

  auto issueA = [&](int buf) {
#pragma unroll
    for (int j = 0; j < AGW; ++j) {
      gload16(aP[j], &lds_a[buf][(wv + j * 4) * 512 + lane * 8]);
      aP[j] += 32;
    }
  };
  auto issueB = [&](int buf) {
#pragma unroll
    for (int j = 0; j < BGW; ++j) {
      gload16(bP[j], &lds_b[buf][(wv + j * 4) * 512 + lane * 8]);
      bP[j] += 32;
    }
  };

  f4v acc[MI][NI];
#pragma unroll
  for (int i = 0; i < MI; ++i)
#pragma unroll
    for (int j = 0; j < NI; ++j) acc[i][j] = (f4v){0.f, 0.f, 0.f, 0.f};

  const int NIT = K / 32;
  // FIFO: A(0), B(0), A(1), B(1)
  issueA(0); issueB(0); issueA(1); issueB(1);

  int ab = 0, bbuf = 0;
  for (int it = 0; it < NIT; ++it) {
    if (it == 0)
      asm volatile("s_waitcnt vmcnt(%0)" ::"n"(AGW + BGW) : "memory");
    else if (it == NIT - 1)
      asm volatile("s_waitcnt vmcnt(0)" ::: "memory");
    else
      asm volatile("s_waitcnt vmcnt(%0)" ::"n"(BGW) : "memory");
    asm volatile("s_barrier" ::: "memory");
    // post-barrier: all waves done compute(it-1) -> old buffers rotatable
    if (it >= 1 && it + 1 < NIT) issueA((it + 1) & 1);
    if (it + 2 < NIT) issueB(bbuf == 0 ? 2 : bbuf - 1);  // (it+2)%3

    s8v af[MI], bfr[NI];
#pragma unroll
    for (int mi = 0; mi < MI; ++mi)
      af[mi] = *(const s8v*)&lds_a[ab][((wm * MI + mi) * 64 + lane) * 8];
#pragma unroll
    for (int ni = 0; ni < NI; ++ni)
      bfr[ni] = *(const s8v*)&lds_b[bbuf][((wn * NI + ni) * 64 + lane) * 8];
#pragma unroll
    for (int mi = 0; mi < MI; ++mi)
#pragma unroll
      for (int ni = 0; ni < NI; ++ni)
        acc[mi][ni] = __builtin_amdgcn_mfma_f32_16x16x32_bf16(
            af[mi], bfr[ni], acc[mi][ni], 0, 0, 0);
    ab ^= 1;
    bbuf = bbuf == 2 ? 0 : bbuf + 1;
  }

  const int quad = lane >> 4, col = lane & 15;
#pragma unroll
  for (int mi = 0; mi < MI; ++mi) {
#pragma unroll
    for (int ni = 0; ni < NI; ++ni) {
      int n = bn + wn * (BN / 2) + ni * 16 + col;
      int m0 = bm + wm * (BM / 2) + mi * 16 + quad * 4;
      f4v vv = acc[mi][ni];
#pragma unroll
      for (int r2 = 0; r2 < 4; ++r2) {
        int m = m0 + r2;
        float val = vv[r2];
        if constexpr (MODE == MODE_SCALE) val *= scale;
        if constexpr (MODE == MODE_FINAL) {
          val += b0[m] + resid[(long)bz * sR + (long)m * N + n];
          ((float*)Cg)[c_off + (long)m * N + n] = val;
        } else {
          ((u16*)Cg)[c_off + (long)m * N + n] = f2bf(val);
        }
      }
    }
  }
  (void)scale; (void)resid;
}

extern "C" void kernel_launch(void* const* d_in, const int* in_sizes, int n_in,
                              void* d_out, int out_size, void* d_ws,
                              size_t ws_size, hipStream_t stream) {
  const float* x = (const float*)d_in[0];
  const float* gamma = (const float*)d_in[1];
  const float* beta = (const float*)d_in[2];
  const float* wq = (const float*)d_in[3];
  const float* bq = (const float*)d_in[4];
  const float* wk = (const float*)d_in[5];
  const float* bk = (const float*)d_in[6];
  const float* wv = (const float*)d_in[7];
  const float* bv = (const float*)d_in[8];
  const float* wo = (const float*)d_in[9];
  const float* bo = (const float*)d_in[10];

  u16* ws = (u16*)d_ws;
  u16* hnt = ws;            // [2][4096][512]; after QKV free; reduce -> out_t
  u16* qt = ws + 4194304;   // q_t; during PV: split-K partial ks=0
  u16* kt = ws + 8388608;   // k_t; during PV: split-K partial ks=1
  u16* vt = ws + 12582912;  // v [2][512][4096] (written transposed by QKV)
  u16* S = ws + 16777216;   // [2][4096][4096] bf16
  u16* wqb = ws + 50331648; // 4 weights bf16
  u16* wob = ws + 51118080;
  float2* part = (float2*)((char*)d_ws + 102760448);
  float2* AB = (float2*)((char*)d_ws + 102764544);

  w2bf<<<dim3(256, 4), 256, 0, stream>>>(wq, wk, wv, wo, wqb);
  gn_stats<<<512, 256, 0, stream>>>(x, part);
  gn_ab<<<4, 256, 0, stream>>>(part, gamma, beta, AB);
  gn_apply_t<<<dim3(128, 16, 2), 256, 0, stream>>>(x, AB, hnt);

  // fused q/k/v: 512 blocks
  gemm_qkv3<<<512, 256, 0, stream>>>(hnt, wqb, qt, kt, vt, bq, bk, bv);

  // S = scale * q_t k_t^T: 128x256 tiles, nx=16, nyg=4, nz=2 -> 1024 blocks
  gemm_nt<MODE_SCALE, 128, 256><<<1024, 256, 0, stream>>>(
      qt, 2097152, kt, 2097152, S, 16777216L, 16, 4, 512, 512, 512, 4096,
      nullptr, nullptr, 0, 0.044194173824159216f);

  softmax_rows<<<8192, 256, 0, stream>>>(S);

  // PV split-K=2, 128x128 tiles: nx=4, nyg=4, nz=4 -> 512 blocks
  gemm_nt<MODE_PV, 128, 128><<<512, 256, 0, stream>>>(
      S, 16777216L, vt, 2097152, qt, 2097152, 4, 4, 2048, 4096, 4096, 512,
      nullptr, nullptr, 0, 0.f);

  // out_t = partial0 + partial1 -> hnt slot
  reduce_pv<<<2048, 256, 0, stream>>>(qt, hnt);

  // d_out = wo . out_t^T + bo + x: 64x128, nx=32, nyg=1, nz=2 -> 512 blocks
  gemm_nt<MODE_FINAL, 64, 128><<<512, 256, 0, stream>>>(
      wob, 0, hnt, 2097152, d_out, 2097152, 32, 1, 512, 512, 512, 4096, bo,
      x, 2097152, 0.f);

  (void)in_sizes; (void)n_in; (void)out_size; (void)ws_size;
}

// Round 8
// 301.409 us; speedup vs baseline: 1.0774x; 1.0774x over previous
//
#include <hip/hip_runtime.h>

typedef unsigned short u16;
typedef unsigned char u8;
typedef __attribute__((ext_vector_type(8))) short s8v;
typedef __attribute__((ext_vector_type(4))) float f4v;

enum { MODE_SCALE = 2, MODE_FINAL = 3 };

__device__ __forceinline__ u16 f2bf(float f) {
  unsigned u = __builtin_bit_cast(unsigned, f);
  u += 0x7fffu + ((u >> 16) & 1u);
  return (u16)(u >> 16);
}
__device__ __forceinline__ float bf2f(u16 h) {
  unsigned u = ((unsigned)h) << 16;
  return __builtin_bit_cast(float, u);
}
__device__ __forceinline__ void gload16(const void* g, void* l) {
  __builtin_amdgcn_global_load_lds(
      (const __attribute__((address_space(1))) unsigned int*)g,
      (__attribute__((address_space(3))) unsigned int*)l, 16, 0, 0);
}
// pack 4 floats -> 4 fp8 e4m3 (OCP on gfx950)
__device__ __forceinline__ unsigned pk4fp8(float a, float b, float c, float d) {
  int lo = __builtin_amdgcn_cvt_pk_fp8_f32(a, b, 0, false);
  return (unsigned)__builtin_amdgcn_cvt_pk_fp8_f32(c, d, lo, true);
}

// ---------------- weight fp32 -> bf16 ----------------
__global__ __launch_bounds__(256) void w2bf(const float* __restrict__ w0,
                                            const float* __restrict__ w1,
                                            const float* __restrict__ w2,
                                            const float* __restrict__ w3,
                                            u16* __restrict__ out) {
  int which = blockIdx.y;
  const float* w = which == 0 ? w0 : which == 1 ? w1 : which == 2 ? w2 : w3;
  int i = (blockIdx.x * 256 + threadIdx.x) * 4;
  float4 f = *(const float4*)(w + i);
  u16* o = out + (long)which * 262144 + i;
  ushort4 r;
  r.x = f2bf(f.x); r.y = f2bf(f.y); r.z = f2bf(f.z); r.w = f2bf(f.w);
  *(ushort4*)o = r;
}

// ---------------- groupnorm: partial stats ----------------
__global__ __launch_bounds__(256) void gn_stats(const float* __restrict__ x,
                                                float2* __restrict__ part) {
  const int bid = blockIdx.x;
  const float4* p4 = (const float4*)(x + (long)bid * 8192);
  float s = 0.f, q = 0.f;
  int t = threadIdx.x;
#pragma unroll
  for (int j = 0; j < 8; ++j) {
    float4 f = p4[t + 256 * j];
    s += f.x + f.y + f.z + f.w;
    q += f.x * f.x + f.y * f.y + f.z * f.z + f.w * f.w;
  }
#pragma unroll
  for (int o = 32; o; o >>= 1) {
    s += __shfl_xor(s, o, 64);
    q += __shfl_xor(q, o, 64);
  }
  __shared__ float rs[4], rq[4];
  int lane = t & 63, wv = t >> 6;
  if (lane == 0) { rs[wv] = s; rq[wv] = q; }
  __syncthreads();
  if (t == 0)
    part[bid] = make_float2(rs[0] + rs[1] + rs[2] + rs[3],
                            rq[0] + rq[1] + rq[2] + rq[3]);
}

// ---------------- groupnorm: per-channel scale/shift ----------------
__global__ __launch_bounds__(256) void gn_ab(const float2* __restrict__ part,
                                             const float* __restrict__ gamma,
                                             const float* __restrict__ beta,
                                             float2* __restrict__ AB) {
  int idx = blockIdx.x * 256 + threadIdx.x;
  int g = idx >> 4;
  float s = 0.f, q = 0.f;
#pragma unroll
  for (int j = 0; j < 8; ++j) {
    float2 pp = part[g * 8 + j];
    s += pp.x; q += pp.y;
  }
  float mean = s * (1.0f / 65536.0f);
  float var = q * (1.0f / 65536.0f) - mean * mean;
  int c = idx & 511;
  float a = gamma[c] * rsqrtf(var + 1e-6f);
  AB[idx] = make_float2(a, beta[c] - mean * a);
}

// ---------------- apply groupnorm + transpose ----------------
__global__ __launch_bounds__(256) void gn_apply_t(const float* __restrict__ x,
                                                  const float2* __restrict__ AB,
                                                  u16* __restrict__ hnt) {
  int p0 = blockIdx.x * 32, c0 = blockIdx.y * 32, b = blockIdx.z;
  __shared__ float tile[32][33];
  int t = threadIdx.x;
  const float* xb = x + (long)b * 2097152;
#pragma unroll
  for (int j = 0; j < 4; ++j) {
    int lc = (t >> 5) + j * 8, lp = t & 31;
    tile[lc][lp] = xb[(long)(c0 + lc) * 4096 + p0 + lp];
  }
  __syncthreads();
#pragma unroll
  for (int j = 0; j < 4; ++j) {
    int lp = (t >> 5) + j * 8, lc = t & 31;
    float2 ab = AB[b * 512 + c0 + lc];
    float val = tile[lc][lp] * ab.x + ab.y;
    hnt[(long)b * 2097152 + (long)(p0 + lp) * 512 + c0 + lc] = f2bf(val);
  }
}

// ------- softmax: bf16 S row -> fp8 P row scaled by 256 -------------------
__global__ __launch_bounds__(256) void softmax_rows(const u16* __restrict__ S,
                                                    u8* __restrict__ P) {
  const u16* p = S + (long)blockIdx.x * 4096;
  const int t = threadIdx.x;
  s8v h0 = ((const s8v*)p)[t * 2];
  s8v h1 = ((const s8v*)p)[t * 2 + 1];
  float v[16];
#pragma unroll
  for (int j = 0; j < 8; ++j) {
    v[j] = bf2f((u16)h0[j]);
    v[8 + j] = bf2f((u16)h1[j]);
  }
  float mx = v[0];
#pragma unroll
  for (int j = 1; j < 16; ++j) mx = fmaxf(mx, v[j]);
#pragma unroll
  for (int o = 32; o; o >>= 1) mx = fmaxf(mx, __shfl_xor(mx, o, 64));
  __shared__ float red[4], red2[4];
  int lane = t & 63, wv = t >> 6;
  if (lane == 0) red[wv] = mx;
  __syncthreads();
  mx = fmaxf(fmaxf(red[0], red[1]), fmaxf(red[2], red[3]));
  float s = 0.f;
#pragma unroll
  for (int j = 0; j < 16; ++j) {
    v[j] = __expf(v[j] - mx);
    s += v[j];
  }
#pragma unroll
  for (int o = 32; o; o >>= 1) s += __shfl_xor(s, o, 64);
  if (lane == 0) red2[wv] = s;
  __syncthreads();
  s = red2[0] + red2[1] + red2[2] + red2[3];
  float invs = 256.0f / s;  // scale x256: keeps diffuse P out of e4m3 underflow
  uint4 o4;
  o4.x = pk4fp8(v[0] * invs, v[1] * invs, v[2] * invs, v[3] * invs);
  o4.y = pk4fp8(v[4] * invs, v[5] * invs, v[6] * invs, v[7] * invs);
  o4.z = pk4fp8(v[8] * invs, v[9] * invs, v[10] * invs, v[11] * invs);
  o4.w = pk4fp8(v[12] * invs, v[13] * invs, v[14] * invs, v[15] * invs);
  *(uint4*)(P + (long)blockIdx.x * 4096 + t * 16) = o4;
}

// ---------------- split-K4 reduce -> out_t (bf16) -------------------------
__global__ __launch_bounds__(256) void reduce_pv4(const u16* __restrict__ p,
                                                  u16* __restrict__ out) {
  long i = ((long)blockIdx.x * 256 + threadIdx.x) * 8;
  s8v a = *(const s8v*)(p + i);
  s8v b = *(const s8v*)(p + 2097152 + i);
  s8v c = *(const s8v*)(p + 4194304 + i);
  s8v d = *(const s8v*)(p + 6291456 + i);
  s8v o;
#pragma unroll
  for (int j = 0; j < 8; ++j)
    o[j] = (short)f2bf(bf2f((u16)a[j]) + bf2f((u16)b[j]) + bf2f((u16)c[j]) +
                       bf2f((u16)d[j]));
  *(s8v*)(out + i) = o;
}

// ---------------- fused QKV GEMM (v written fp8 [c][p]) -------------------
__global__ __launch_bounds__(256) void gemm_qkv3(
    const u16* __restrict__ hnt, const u16* __restrict__ wqb,
    u16* __restrict__ qt, u16* __restrict__ kt, u8* __restrict__ vt8,
    const float* __restrict__ bq, const float* __restrict__ bk,
    const float* __restrict__ bv) {
  constexpr int MI = 4, NI = 2, AGW = 2, NLD = 5;
  __shared__ __align__(16) u16 la[3][4096];
  __shared__ __align__(16) u16 lb[3][3][2048];
  const int t = threadIdx.x;
  const int lane = t & 63, wv = t >> 6;
  const int wm = wv >> 1, wn = wv & 1;

  int lin = blockIdx.x;
  int xcd = lin & 7, s = lin >> 3;
  int bn_i = s % 8, t2 = s / 8;
  int bm_i = (t2 % 4) * 8 + xcd;
  int bb = t2 / 4;
  const int bm = bm_i * 128, bn = bn_i * 64;

  const u16* A = hnt + (long)bb * 2097152;
  const u16* aP[AGW];
#pragma unroll
  for (int j = 0; j < AGW; ++j)
    aP[j] = A + (long)(bm + (wv + j * 4) * 16 + (lane & 15)) * 512 +
            (lane >> 4) * 8;
  const u16* bP[3];
#pragma unroll
  for (int w = 0; w < 3; ++w)
    bP[w] = wqb + (long)w * 262144 +
            (long)(bn + wv * 16 + (lane & 15)) * 512 + (lane >> 4) * 8;

  auto issue = [&](int buf) {
#pragma unroll
    for (int j = 0; j < AGW; ++j) {
      gload16(aP[j], &la[buf][(wv + j * 4) * 512 + lane * 8]);
      aP[j] += 32;
    }
#pragma unroll
    for (int w = 0; w < 3; ++w) {
      gload16(bP[w], &lb[buf][w][wv * 512 + lane * 8]);
      bP[w] += 32;
    }
  };

  f4v acc[3][MI][NI];
#pragma unroll
  for (int w = 0; w < 3; ++w)
#pragma unroll
    for (int i = 0; i < MI; ++i)
#pragma unroll
      for (int j = 0; j < NI; ++j) acc[w][i][j] = (f4v){0.f, 0.f, 0.f, 0.f};

  issue(0);
  issue(1);
  int cur = 0, nxt = 2;
  for (int it = 0; it < 16; ++it) {
    if (it < 15)
      asm volatile("s_waitcnt vmcnt(%0)" ::"n"(NLD) : "memory");
    else
      asm volatile("s_waitcnt vmcnt(0)" ::: "memory");
    asm volatile("s_barrier" ::: "memory");
    if (it + 2 < 16) issue(nxt);

    s8v af[MI], bfr[3][NI];
#pragma unroll
    for (int mi = 0; mi < MI; ++mi)
      af[mi] = *(const s8v*)&la[cur][((wm * MI + mi) * 64 + lane) * 8];
#pragma unroll
    for (int w = 0; w < 3; ++w)
#pragma unroll
      for (int ni = 0; ni < NI; ++ni)
        bfr[w][ni] =
            *(const s8v*)&lb[cur][w][((wn * NI + ni) * 64 + lane) * 8];
#pragma unroll
    for (int w = 0; w < 3; ++w)
#pragma unroll
      for (int mi = 0; mi < MI; ++mi)
#pragma unroll
        for (int ni = 0; ni < NI; ++ni)
          acc[w][mi][ni] = __builtin_amdgcn_mfma_f32_16x16x32_bf16(
              af[mi], bfr[w][ni], acc[w][mi][ni], 0, 0, 0);
    cur = cur == 2 ? 0 : cur + 1;
    nxt = nxt == 2 ? 0 : nxt + 1;
  }

  const int quad = lane >> 4, col = lane & 15;
#pragma unroll
  for (int w = 0; w < 3; ++w) {
    const float* bias = w == 0 ? bq : w == 1 ? bk : bv;
    u16* dst = w == 0 ? qt : kt;
#pragma unroll
    for (int mi = 0; mi < MI; ++mi) {
#pragma unroll
      for (int ni = 0; ni < NI; ++ni) {
        int n = bn + wn * 32 + ni * 16 + col;
        int m0 = bm + wm * 64 + mi * 16 + quad * 4;
        f4v vv = acc[w][mi][ni];
        float bsv = bias[n];
        if (w == 2) {
          // v fp8: [b][c=n][p=m], 4 consecutive m -> packed 4B store
          *(unsigned*)&vt8[(long)bb * 2097152 + (long)n * 4096 + m0] =
              pk4fp8(vv[0] + bsv, vv[1] + bsv, vv[2] + bsv, vv[3] + bsv);
        } else {
#pragma unroll
          for (int r2 = 0; r2 < 4; ++r2)
            dst[(long)bb * 2097152 + (long)(m0 + r2) * 512 + n] =
                f2bf(vv[r2] + bsv);
        }
      }
    }
  }
}

// ---------------- bf16 NT GEMM (r6 config: symmetric 3-stage) -------------
template <int MODE, int BM, int BN>
__global__ __launch_bounds__(256) void gemm_nt(
    const u16* __restrict__ Ag, long sA, const u16* __restrict__ Btg, long sB,
    void* __restrict__ Cg, long sC, int nx, int nyg, int K, long lda, long ldb,
    int N, const float* __restrict__ b0, const float* __restrict__ resid,
    long sR, float scale) {
  constexpr int MI = BM / 32, NI = BN / 32;
  constexpr int AGW = BM / 64, BGW = BN / 64;
  constexpr int NLD = AGW + BGW;
  __shared__ __align__(16) u16 lds_a[3][BM * 32];
  __shared__ __align__(16) u16 lds_b[3][BN * 32];
  const int t = threadIdx.x;
  const int lane = t & 63, wv = t >> 6;
  const int wm = wv >> 1, wn = wv & 1;

  int lin = blockIdx.x;
  int xcd = lin & 7, s = lin >> 3;
  int bn_i = s % nx, t2 = s / nx;
  int bm_i = (t2 % nyg) * 8 + xcd;
  int bz = t2 / nyg;

  const u16* A = Ag + (long)bz * sA;
  const u16* Bt = Btg + (long)bz * sB;
  long c_off = (long)bz * sC;
  const int bm = bm_i * BM, bn = bn_i * BN;

  const u16* aP[AGW];
  const u16* bP[BGW];
#pragma unroll
  for (int j = 0; j < AGW; ++j)
    aP[j] = A + (long)(bm + (wv + j * 4) * 16 + (lane & 15)) * lda +
            (lane >> 4) * 8;
#pragma unroll
  for (int j = 0; j < BGW; ++j)
    bP[j] = Bt + (long)(bn + (wv + j * 4) * 16 + (lane & 15)) * ldb +
            (lane >> 4) * 8;

  auto issue = [&](int buf) {
#pragma unroll
    for (int j = 0; j < AGW; ++j) {
      gload16(aP[j], &lds_a[buf][(wv + j * 4) * 512 + lane * 8]);
      aP[j] += 32;
    }
#pragma unroll
    for (int j = 0; j < BGW; ++j) {
      gload16(bP[j], &lds_b[buf][(wv + j * 4) * 512 + lane * 8]);
      bP[j] += 32;
    }
  };

  f4v acc[MI][NI];
#pragma unroll
  for (int i = 0; i < MI; ++i)
#pragma unroll
    for (int j = 0; j < NI; ++j) acc[i][j] = (f4v){0.f, 0.f, 0.f, 0.f};

  const int NIT = K / 32;
  issue(0);
  issue(1);
  int cur = 0, nxt = 2;
  for (int it = 0; it < NIT; ++it) {
    if (it < NIT - 1)
      asm volatile("s_waitcnt vmcnt(%0)" ::"n"(NLD) : "memory");
    else
      asm volatile("s_waitcnt vmcnt(0)" ::: "memory");
    asm volatile("s_barrier" ::: "memory");
    if (it + 2 < NIT) issue(nxt);

    s8v af[MI], bfr[NI];
#pragma unroll
    for (int mi = 0; mi < MI; ++mi)
      af[mi] = *(const s8v*)&lds_a[cur][((wm * MI + mi) * 64 + lane) * 8];
#pragma unroll
    for (int ni = 0; ni < NI; ++ni)
      bfr[ni] = *(const s8v*)&lds_b[cur][((wn * NI + ni) * 64 + lane) * 8];
#pragma unroll
    for (int mi = 0; mi < MI; ++mi)
#pragma unroll
      for (int ni = 0; ni < NI; ++ni)
        acc[mi][ni] = __builtin_amdgcn_mfma_f32_16x16x32_bf16(
            af[mi], bfr[ni], acc[mi][ni], 0, 0, 0);
    cur = cur == 2 ? 0 : cur + 1;
    nxt = nxt == 2 ? 0 : nxt + 1;
  }

  const int quad = lane >> 4, col = lane & 15;
#pragma unroll
  for (int mi = 0; mi < MI; ++mi) {
#pragma unroll
    for (int ni = 0; ni < NI; ++ni) {
      int n = bn + wn * (BN / 2) + ni * 16 + col;
      int m0 = bm + wm * (BM / 2) + mi * 16 + quad * 4;
      f4v vv = acc[mi][ni];
#pragma unroll
      for (int r2 = 0; r2 < 4; ++r2) {
        int m = m0 + r2;
        float val = vv[r2];
        if constexpr (MODE == MODE_SCALE) val *= scale;
        if constexpr (MODE == MODE_FINAL) {
          val += b0[m] + resid[(long)bz * sR + (long)m * N + n];
          ((float*)Cg)[c_off + (long)m * N + n] = val;
        } else {
          ((u16*)Cg)[c_off + (long)m * N + n] = f2bf(val);
        }
      }
    }
  }
  (void)scale; (void)resid;
}

// ---------------- fp8 PV GEMM: partial[ks] = P[.,ksK]*V^T[.,ksK] ----------
// A = P fp8 [4096][4096], B = v fp8 [512][4096]; 128x128 tile, split-K4.
// Staging permuted so fragment ds_read_b64 is 2-way (free). 24KB LDS.
__global__ __launch_bounds__(256) void gemm_pv8(const u8* __restrict__ P,
                                                const u8* __restrict__ V,
                                                u16* __restrict__ part) {
  __shared__ __align__(16) u8 pa[3][4096];
  __shared__ __align__(16) u8 pb[3][4096];
  const int t = threadIdx.x;
  const int lane = t & 63, wv = t >> 6;
  const int wm = wv >> 1, wn = wv & 1;

  int lin = blockIdx.x;
  int xcd = lin & 7, s = lin >> 3;
  int bn_i = s % 4, t2 = s / 4;
  int bm_i = (t2 % 4) * 8 + xcd;
  int ks = t2 / 4;
  const int bm = bm_i * 128, bn = bn_i * 128;

  // staging: lane covers row (lane&15)+16*(lane>>5) of wave's 32-row chunk,
  // k-halves ((lane>>4)&1)*16; dest = t*16 (wave-uniform + lane*16).
  const int srow = (lane & 15) + 16 * (lane >> 5);
  const int skof = ((lane >> 4) & 1) * 16;
  const u8* aP = P + (long)(bm + wv * 32 + srow) * 4096 + ks * 1024 + skof;
  const u8* bP = V + (long)(bn + wv * 32 + srow) * 4096 + ks * 1024 + skof;

  auto issue = [&](int buf) {
    gload16(aP, &pa[buf][t * 16]);
    aP += 32;
    gload16(bP, &pb[buf][t * 16]);
    bP += 32;
  };

  f4v acc[4][4];
#pragma unroll
  for (int i = 0; i < 4; ++i)
#pragma unroll
    for (int j = 0; j < 4; ++j) acc[i][j] = (f4v){0.f, 0.f, 0.f, 0.f};

  issue(0);
  issue(1);
  int cur = 0, nxt = 2;
  const int quad = lane >> 4, qh = quad >> 1, ql = quad & 1, r16 = lane & 15;
  const int fbase = qh * 256 + r16 * 16 + ql * 8;
  for (int it = 0; it < 32; ++it) {
    if (it < 31)
      asm volatile("s_waitcnt vmcnt(2)" ::: "memory");
    else
      asm volatile("s_waitcnt vmcnt(0)" ::: "memory");
    asm volatile("s_barrier" ::: "memory");
    if (it + 2 < 32) issue(nxt);

    long af[4], bf[4];
#pragma unroll
    for (int mi = 0; mi < 4; ++mi) {
      int gg = wm * 4 + mi;
      af[mi] = *(const long*)&pa[cur][(gg >> 1) * 1024 + (gg & 1) * 512 + fbase];
    }
#pragma unroll
    for (int ni = 0; ni < 4; ++ni) {
      int gg = wn * 4 + ni;
      bf[ni] = *(const long*)&pb[cur][(gg >> 1) * 1024 + (gg & 1) * 512 + fbase];
    }
#pragma unroll
    for (int mi = 0; mi < 4; ++mi)
#pragma unroll
      for (int ni = 0; ni < 4; ++ni)
        acc[mi][ni] = __builtin_amdgcn_mfma_f32_16x16x32_fp8_fp8(
            af[mi], bf[ni], acc[mi][ni], 0, 0, 0);
    cur = cur == 2 ? 0 : cur + 1;
    nxt = nxt == 2 ? 0 : nxt + 1;
  }

  u16* dst = part + (long)ks * 2097152;
#pragma unroll
  for (int mi = 0; mi < 4; ++mi) {
#pragma unroll
    for (int ni = 0; ni < 4; ++ni) {
      int n = bn + wn * 64 + ni * 16 + (lane & 15);
      int m0 = bm + wm * 64 + mi * 16 + quad * 4;
      f4v vv = acc[mi][ni];
#pragma unroll
      for (int r2 = 0; r2 < 4; ++r2)
        dst[(long)(m0 + r2) * 512 + n] = f2bf(vv[r2] * 0.00390625f);
    }
  }
}

extern "C" void kernel_launch(void* const* d_in, const int* in_sizes, int n_in,
                              void* d_out, int out_size, void* d_ws,
                              size_t ws_size, hipStream_t stream) {
  const float* x = (const float*)d_in[0];
  const float* gamma = (const float*)d_in[1];
  const float* beta = (const float*)d_in[2];
  const float* wq = (const float*)d_in[3];
  const float* bq = (const float*)d_in[4];
  const float* wk = (const float*)d_in[5];
  const float* bk = (const float*)d_in[6];
  const float* wv = (const float*)d_in[7];
  const float* bv = (const float*)d_in[8];
  const float* wo = (const float*)d_in[9];
  const float* bo = (const float*)d_in[10];

  u16* ws = (u16*)d_ws;
  u16* hnt = ws;             // [2][4096][512] bf16; later out_t
  u16* qt = ws + 4194304;    // q_t bf16
  u16* kt = ws + 8388608;    // k_t bf16
  u8* vt8 = (u8*)(ws + 12582912);  // v fp8 [2][512][4096] (4MB of 8MB slot)
  u16* S = ws + 16777216;    // per-batch S bf16 [4096][4096] = 32MB
  u8* P8 = (u8*)(ws + 33554432);   // per-batch P fp8 [4096][4096] = 16MB
  u16* parts = ws + 41943040;      // split-K4 partials 4x[4096][512] bf16
  u16* wqb = ws + 50331648;  // 4 weights bf16
  u16* wob = ws + 51118080;
  float2* part = (float2*)((char*)d_ws + 102760448);
  float2* AB = (float2*)((char*)d_ws + 102764544);

  w2bf<<<dim3(256, 4), 256, 0, stream>>>(wq, wk, wv, wo, wqb);
  gn_stats<<<512, 256, 0, stream>>>(x, part);
  gn_ab<<<4, 256, 0, stream>>>(part, gamma, beta, AB);
  gn_apply_t<<<dim3(128, 16, 2), 256, 0, stream>>>(x, AB, hnt);

  // fused q/k/v (v -> fp8): 512 blocks
  gemm_qkv3<<<512, 256, 0, stream>>>(hnt, wqb, qt, kt, vt8, bq, bk, bv);

  for (int b = 0; b < 2; ++b) {
    // S = scale * q_t k_t^T (one batch): 1024 blocks
    gemm_nt<MODE_SCALE, 128, 128><<<1024, 256, 0, stream>>>(
        qt + (long)b * 2097152, 0, kt + (long)b * 2097152, 0, S, 0, 32, 4,
        512, 512, 512, 4096, nullptr, nullptr, 0, 0.044194173824159216f);
    // softmax -> P fp8 (x256)
    softmax_rows<<<4096, 256, 0, stream>>>(S, P8);
    // PV fp8 split-K4: 512 blocks
    gemm_pv8<<<512, 256, 0, stream>>>(P8, vt8 + (long)b * 2097152, parts);
    // out_t[b] = sum of 4 partials
    reduce_pv4<<<1024, 256, 0, stream>>>(parts, hnt + (long)b * 2097152);
  }

  // d_out = wo . out_t^T + bo + x: 64x128, nx=32, nyg=1, nz=2 -> 512 blocks
  gemm_nt<MODE_FINAL, 64, 128><<<512, 256, 0, stream>>>(
      wob, 0, hnt, 2097152, d_out, 2097152, 32, 1, 512, 512, 512, 4096, bo,
      x, 2097152, 0.f);

  (void)in_sizes; (void)n_in; (void)out_size; (void)ws_size;
}

// Round 9
// 270.286 us; speedup vs baseline: 1.2014x; 1.1151x over previous
//
#include <hip/hip_runtime.h>

typedef unsigned short u16;
typedef unsigned char u8;
typedef __attribute__((ext_vector_type(8))) short s8v;
typedef __attribute__((ext_vector_type(4))) float f4v;

enum { MODE_SCALE = 2, MODE_FINAL = 3 };

__device__ __forceinline__ u16 f2bf(float f) {
  unsigned u = __builtin_bit_cast(unsigned, f);
  u += 0x7fffu + ((u >> 16) & 1u);
  return (u16)(u >> 16);
}
__device__ __forceinline__ float bf2f(u16 h) {
  unsigned u = ((unsigned)h) << 16;
  return __builtin_bit_cast(float, u);
}
__device__ __forceinline__ void gload16(const void* g, void* l) {
  __builtin_amdgcn_global_load_lds(
      (const __attribute__((address_space(1))) unsigned int*)g,
      (__attribute__((address_space(3))) unsigned int*)l, 16, 0, 0);
}
// pack 4 floats -> 4 fp8 e4m3 (OCP on gfx950)
__device__ __forceinline__ unsigned pk4fp8(float a, float b, float c, float d) {
  int lo = __builtin_amdgcn_cvt_pk_fp8_f32(a, b, 0, false);
  return (unsigned)__builtin_amdgcn_cvt_pk_fp8_f32(c, d, lo, true);
}
__device__ __forceinline__ u8 f2fp8(float a) {
  return (u8)(__builtin_amdgcn_cvt_pk_fp8_f32(a, a, 0, false) & 0xff);
}

// ---------------- weight fp32 -> bf16 ----------------
__global__ __launch_bounds__(256) void w2bf(const float* __restrict__ w0,
                                            const float* __restrict__ w1,
                                            const float* __restrict__ w2,
                                            const float* __restrict__ w3,
                                            u16* __restrict__ out) {
  int which = blockIdx.y;
  const float* w = which == 0 ? w0 : which == 1 ? w1 : which == 2 ? w2 : w3;
  int i = (blockIdx.x * 256 + threadIdx.x) * 4;
  float4 f = *(const float4*)(w + i);
  u16* o = out + (long)which * 262144 + i;
  ushort4 r;
  r.x = f2bf(f.x); r.y = f2bf(f.y); r.z = f2bf(f.z); r.w = f2bf(f.w);
  *(ushort4*)o = r;
}

// ---------------- groupnorm: partial stats ----------------
__global__ __launch_bounds__(256) void gn_stats(const float* __restrict__ x,
                                                float2* __restrict__ part) {
  const int bid = blockIdx.x;
  const float4* p4 = (const float4*)(x + (long)bid * 8192);
  float s = 0.f, q = 0.f;
  int t = threadIdx.x;
#pragma unroll
  for (int j = 0; j < 8; ++j) {
    float4 f = p4[t + 256 * j];
    s += f.x + f.y + f.z + f.w;
    q += f.x * f.x + f.y * f.y + f.z * f.z + f.w * f.w;
  }
#pragma unroll
  for (int o = 32; o; o >>= 1) {
    s += __shfl_xor(s, o, 64);
    q += __shfl_xor(q, o, 64);
  }
  __shared__ float rs[4], rq[4];
  int lane = t & 63, wv = t >> 6;
  if (lane == 0) { rs[wv] = s; rq[wv] = q; }
  __syncthreads();
  if (t == 0)
    part[bid] = make_float2(rs[0] + rs[1] + rs[2] + rs[3],
                            rq[0] + rq[1] + rq[2] + rq[3]);
}

// ---------------- groupnorm: per-channel scale/shift ----------------
__global__ __launch_bounds__(256) void gn_ab(const float2* __restrict__ part,
                                             const float* __restrict__ gamma,
                                             const float* __restrict__ beta,
                                             float2* __restrict__ AB) {
  int idx = blockIdx.x * 256 + threadIdx.x;
  int g = idx >> 4;
  float s = 0.f, q = 0.f;
#pragma unroll
  for (int j = 0; j < 8; ++j) {
    float2 pp = part[g * 8 + j];
    s += pp.x; q += pp.y;
  }
  float mean = s * (1.0f / 65536.0f);
  float var = q * (1.0f / 65536.0f) - mean * mean;
  int c = idx & 511;
  float a = gamma[c] * rsqrtf(var + 1e-6f);
  AB[idx] = make_float2(a, beta[c] - mean * a);
}

// ---------------- apply groupnorm + transpose ----------------
__global__ __launch_bounds__(256) void gn_apply_t(const float* __restrict__ x,
                                                  const float2* __restrict__ AB,
                                                  u16* __restrict__ hnt) {
  int p0 = blockIdx.x * 32, c0 = blockIdx.y * 32, b = blockIdx.z;
  __shared__ float tile[32][33];
  int t = threadIdx.x;
  const float* xb = x + (long)b * 2097152;
#pragma unroll
  for (int j = 0; j < 4; ++j) {
    int lc = (t >> 5) + j * 8, lp = t & 31;
    tile[lc][lp] = xb[(long)(c0 + lc) * 4096 + p0 + lp];
  }
  __syncthreads();
#pragma unroll
  for (int j = 0; j < 4; ++j) {
    int lp = (t >> 5) + j * 8, lc = t & 31;
    float2 ab = AB[b * 512 + c0 + lc];
    float val = tile[lc][lp] * ab.x + ab.y;
    hnt[(long)b * 2097152 + (long)(p0 + lp) * 512 + c0 + lc] = f2bf(val);
  }
}

// ------- softmax: bf16 S row -> fp8 P row scaled by 256 -------------------
__global__ __launch_bounds__(256) void softmax_rows(const u16* __restrict__ S,
                                                    u8* __restrict__ P) {
  const u16* p = S + (long)blockIdx.x * 4096;
  const int t = threadIdx.x;
  s8v h0 = ((const s8v*)p)[t * 2];
  s8v h1 = ((const s8v*)p)[t * 2 + 1];
  float v[16];
#pragma unroll
  for (int j = 0; j < 8; ++j) {
    v[j] = bf2f((u16)h0[j]);
    v[8 + j] = bf2f((u16)h1[j]);
  }
  float mx = v[0];
#pragma unroll
  for (int j = 1; j < 16; ++j) mx = fmaxf(mx, v[j]);
#pragma unroll
  for (int o = 32; o; o >>= 1) mx = fmaxf(mx, __shfl_xor(mx, o, 64));
  __shared__ float red[4], red2[4];
  int lane = t & 63, wv = t >> 6;
  if (lane == 0) red[wv] = mx;
  __syncthreads();
  mx = fmaxf(fmaxf(red[0], red[1]), fmaxf(red[2], red[3]));
  float s = 0.f;
#pragma unroll
  for (int j = 0; j < 16; ++j) {
    v[j] = __expf(v[j] - mx);
    s += v[j];
  }
#pragma unroll
  for (int o = 32; o; o >>= 1) s += __shfl_xor(s, o, 64);
  if (lane == 0) red2[wv] = s;
  __syncthreads();
  s = red2[0] + red2[1] + red2[2] + red2[3];
  float invs = 256.0f / s;  // x256 keeps diffuse P out of e4m3 underflow
  uint4 o4;
  o4.x = pk4fp8(v[0] * invs, v[1] * invs, v[2] * invs, v[3] * invs);
  o4.y = pk4fp8(v[4] * invs, v[5] * invs, v[6] * invs, v[7] * invs);
  o4.z = pk4fp8(v[8] * invs, v[9] * invs, v[10] * invs, v[11] * invs);
  o4.w = pk4fp8(v[12] * invs, v[13] * invs, v[14] * invs, v[15] * invs);
  *(uint4*)(P + (long)blockIdx.x * 4096 + t * 16) = o4;
}

// ---------------- split-K4 reduce -> out_t (bf16) -------------------------
__global__ __launch_bounds__(256) void reduce_pv4(const u16* __restrict__ p,
                                                  u16* __restrict__ out) {
  long i = ((long)blockIdx.x * 256 + threadIdx.x) * 8;
  s8v a = *(const s8v*)(p + i);
  s8v b = *(const s8v*)(p + 2097152 + i);
  s8v c = *(const s8v*)(p + 4194304 + i);
  s8v d = *(const s8v*)(p + 6291456 + i);
  s8v o;
#pragma unroll
  for (int j = 0; j < 8; ++j)
    o[j] = (short)f2bf(bf2f((u16)a[j]) + bf2f((u16)b[j]) + bf2f((u16)c[j]) +
                       bf2f((u16)d[j]));
  *(s8v*)(out + i) = o;
}

// ---------------- fused QKV GEMM: q,k,v all written fp8 -------------------
// q8,k8: [b][p][c] fp8 (byte scatter, 16B/quad coalesced); v8: [b][c][p].
__global__ __launch_bounds__(256) void gemm_qkv3(
    const u16* __restrict__ hnt, const u16* __restrict__ wqb,
    u8* __restrict__ q8, u8* __restrict__ k8, u8* __restrict__ v8,
    const float* __restrict__ bq, const float* __restrict__ bk,
    const float* __restrict__ bv) {
  constexpr int MI = 4, NI = 2, AGW = 2, NLD = 5;
  __shared__ __align__(16) u16 la[3][4096];
  __shared__ __align__(16) u16 lb[3][3][2048];
  const int t = threadIdx.x;
  const int lane = t & 63, wv = t >> 6;
  const int wm = wv >> 1, wn = wv & 1;

  int lin = blockIdx.x;
  int xcd = lin & 7, s = lin >> 3;
  int bn_i = s % 8, t2 = s / 8;
  int bm_i = (t2 % 4) * 8 + xcd;
  int bb = t2 / 4;
  const int bm = bm_i * 128, bn = bn_i * 64;

  const u16* A = hnt + (long)bb * 2097152;
  const u16* aP[AGW];
#pragma unroll
  for (int j = 0; j < AGW; ++j)
    aP[j] = A + (long)(bm + (wv + j * 4) * 16 + (lane & 15)) * 512 +
            (lane >> 4) * 8;
  const u16* bP[3];
#pragma unroll
  for (int w = 0; w < 3; ++w)
    bP[w] = wqb + (long)w * 262144 +
            (long)(bn + wv * 16 + (lane & 15)) * 512 + (lane >> 4) * 8;

  auto issue = [&](int buf) {
#pragma unroll
    for (int j = 0; j < AGW; ++j) {
      gload16(aP[j], &la[buf][(wv + j * 4) * 512 + lane * 8]);
      aP[j] += 32;
    }
#pragma unroll
    for (int w = 0; w < 3; ++w) {
      gload16(bP[w], &lb[buf][w][wv * 512 + lane * 8]);
      bP[w] += 32;
    }
  };

  f4v acc[3][MI][NI];
#pragma unroll
  for (int w = 0; w < 3; ++w)
#pragma unroll
    for (int i = 0; i < MI; ++i)
#pragma unroll
      for (int j = 0; j < NI; ++j) acc[w][i][j] = (f4v){0.f, 0.f, 0.f, 0.f};

  issue(0);
  issue(1);
  int cur = 0, nxt = 2;
  for (int it = 0; it < 16; ++it) {
    if (it < 15)
      asm volatile("s_waitcnt vmcnt(%0)" ::"n"(NLD) : "memory");
    else
      asm volatile("s_waitcnt vmcnt(0)" ::: "memory");
    asm volatile("s_barrier" ::: "memory");
    if (it + 2 < 16) issue(nxt);

    s8v af[MI], bfr[3][NI];
#pragma unroll
    for (int mi = 0; mi < MI; ++mi)
      af[mi] = *(const s8v*)&la[cur][((wm * MI + mi) * 64 + lane) * 8];
#pragma unroll
    for (int w = 0; w < 3; ++w)
#pragma unroll
      for (int ni = 0; ni < NI; ++ni)
        bfr[w][ni] =
            *(const s8v*)&lb[cur][w][((wn * NI + ni) * 64 + lane) * 8];
#pragma unroll
    for (int w = 0; w < 3; ++w)
#pragma unroll
      for (int mi = 0; mi < MI; ++mi)
#pragma unroll
        for (int ni = 0; ni < NI; ++ni)
          acc[w][mi][ni] = __builtin_amdgcn_mfma_f32_16x16x32_bf16(
              af[mi], bfr[w][ni], acc[w][mi][ni], 0, 0, 0);
    cur = cur == 2 ? 0 : cur + 1;
    nxt = nxt == 2 ? 0 : nxt + 1;
  }

  const int quad = lane >> 4, col = lane & 15;
#pragma unroll
  for (int w = 0; w < 3; ++w) {
    const float* bias = w == 0 ? bq : w == 1 ? bk : bv;
    u8* dst = w == 0 ? q8 : k8;
#pragma unroll
    for (int mi = 0; mi < MI; ++mi) {
#pragma unroll
      for (int ni = 0; ni < NI; ++ni) {
        int n = bn + wn * 32 + ni * 16 + col;
        int m0 = bm + wm * 64 + mi * 16 + quad * 4;
        f4v vv = acc[w][mi][ni];
        float bsv = bias[n];
        if (w == 2) {
          // v fp8: [b][c=n][p=m], 4 consecutive m -> packed 4B store
          *(unsigned*)&v8[(long)bb * 2097152 + (long)n * 4096 + m0] =
              pk4fp8(vv[0] + bsv, vv[1] + bsv, vv[2] + bsv, vv[3] + bsv);
        } else {
          // q/k fp8 [b][p=m][c=n]: byte scatter, 16 lanes -> 16B contiguous
#pragma unroll
          for (int r2 = 0; r2 < 4; ++r2)
            dst[(long)bb * 2097152 + (long)(m0 + r2) * 512 + n] =
                f2fp8(vv[r2] + bsv);
        }
      }
    }
  }
}

// ---------------- fp8 scores GEMM: S = scale * q8 k8^T (one batch) --------
// 128x128 tile, K=512 (NIT=16). Staging/fragment scheme identical to the
// verified gemm_pv8. q8+k8 (4MB/batch) become L2-resident under the swizzle.
__global__ __launch_bounds__(256) void gemm_sc8(const u8* __restrict__ q8,
                                                const u8* __restrict__ k8,
                                                u16* __restrict__ S) {
  __shared__ __align__(16) u8 pa[3][4096];
  __shared__ __align__(16) u8 pb[3][4096];
  const int t = threadIdx.x;
  const int lane = t & 63, wv = t >> 6;
  const int wm = wv >> 1, wn = wv & 1;

  int lin = blockIdx.x;
  int xcd = lin & 7, s = lin >> 3;
  int bn_i = s % 32, t2 = s / 32;  // t2 in [0,4)
  int bm_i = t2 * 8 + xcd;
  const int bm = bm_i * 128, bn = bn_i * 128;

  const int srow = (lane & 15) + 16 * (lane >> 5);
  const int skof = ((lane >> 4) & 1) * 16;
  const u8* aP = q8 + (long)(bm + wv * 32 + srow) * 512 + skof;
  const u8* bP = k8 + (long)(bn + wv * 32 + srow) * 512 + skof;

  auto issue = [&](int buf) {
    gload16(aP, &pa[buf][t * 16]);
    aP += 32;
    gload16(bP, &pb[buf][t * 16]);
    bP += 32;
  };

  f4v acc[4][4];
#pragma unroll
  for (int i = 0; i < 4; ++i)
#pragma unroll
    for (int j = 0; j < 4; ++j) acc[i][j] = (f4v){0.f, 0.f, 0.f, 0.f};

  issue(0);
  issue(1);
  int cur = 0, nxt = 2;
  const int quad = lane >> 4, qh = quad >> 1, ql = quad & 1, r16 = lane & 15;
  const int fbase = qh * 256 + r16 * 16 + ql * 8;
  for (int it = 0; it < 16; ++it) {
    if (it < 15)
      asm volatile("s_waitcnt vmcnt(2)" ::: "memory");
    else
      asm volatile("s_waitcnt vmcnt(0)" ::: "memory");
    asm volatile("s_barrier" ::: "memory");
    if (it + 2 < 16) issue(nxt);

    long af[4], bf[4];
#pragma unroll
    for (int mi = 0; mi < 4; ++mi) {
      int gg = wm * 4 + mi;
      af[mi] = *(const long*)&pa[cur][(gg >> 1) * 1024 + (gg & 1) * 512 + fbase];
    }
#pragma unroll
    for (int ni = 0; ni < 4; ++ni) {
      int gg = wn * 4 + ni;
      bf[ni] = *(const long*)&pb[cur][(gg >> 1) * 1024 + (gg & 1) * 512 + fbase];
    }
#pragma unroll
    for (int mi = 0; mi < 4; ++mi)
#pragma unroll
      for (int ni = 0; ni < 4; ++ni)
        acc[mi][ni] = __builtin_amdgcn_mfma_f32_16x16x32_fp8_fp8(
            af[mi], bf[ni], acc[mi][ni], 0, 0, 0);
    cur = cur == 2 ? 0 : cur + 1;
    nxt = nxt == 2 ? 0 : nxt + 1;
  }

#pragma unroll
  for (int mi = 0; mi < 4; ++mi) {
#pragma unroll
    for (int ni = 0; ni < 4; ++ni) {
      int n = bn + wn * 64 + ni * 16 + r16;
      int m0 = bm + wm * 64 + mi * 16 + quad * 4;
      f4v vv = acc[mi][ni];
#pragma unroll
      for (int r2 = 0; r2 < 4; ++r2)
        S[(long)(m0 + r2) * 4096 + n] = f2bf(vv[r2] * 0.044194173824159216f);
    }
  }
}

// ---------------- fp8 PV GEMM (verified r8): split-K4 ---------------------
__global__ __launch_bounds__(256) void gemm_pv8(const u8* __restrict__ P,
                                                const u8* __restrict__ V,
                                                u16* __restrict__ part) {
  __shared__ __align__(16) u8 pa[3][4096];
  __shared__ __align__(16) u8 pb[3][4096];
  const int t = threadIdx.x;
  const int lane = t & 63, wv = t >> 6;
  const int wm = wv >> 1, wn = wv & 1;

  int lin = blockIdx.x;
  int xcd = lin & 7, s = lin >> 3;
  int bn_i = s % 4, t2 = s / 4;
  int bm_i = (t2 % 4) * 8 + xcd;
  int ks = t2 / 4;
  const int bm = bm_i * 128, bn = bn_i * 128;

  const int srow = (lane & 15) + 16 * (lane >> 5);
  const int skof = ((lane >> 4) & 1) * 16;
  const u8* aP = P + (long)(bm + wv * 32 + srow) * 4096 + ks * 1024 + skof;
  const u8* bP = V + (long)(bn + wv * 32 + srow) * 4096 + ks * 1024 + skof;

  auto issue = [&](int buf) {
    gload16(aP, &pa[buf][t * 16]);
    aP += 32;
    gload16(bP, &pb[buf][t * 16]);
    bP += 32;
  };

  f4v acc[4][4];
#pragma unroll
  for (int i = 0; i < 4; ++i)
#pragma unroll
    for (int j = 0; j < 4; ++j) acc[i][j] = (f4v){0.f, 0.f, 0.f, 0.f};

  issue(0);
  issue(1);
  int cur = 0, nxt = 2;
  const int quad = lane >> 4, qh = quad >> 1, ql = quad & 1, r16 = lane & 15;
  const int fbase = qh * 256 + r16 * 16 + ql * 8;
  for (int it = 0; it < 32; ++it) {
    if (it < 31)
      asm volatile("s_waitcnt vmcnt(2)" ::: "memory");
    else
      asm volatile("s_waitcnt vmcnt(0)" ::: "memory");
    asm volatile("s_barrier" ::: "memory");
    if (it + 2 < 32) issue(nxt);

    long af[4], bf[4];
#pragma unroll
    for (int mi = 0; mi < 4; ++mi) {
      int gg = wm * 4 + mi;
      af[mi] = *(const long*)&pa[cur][(gg >> 1) * 1024 + (gg & 1) * 512 + fbase];
    }
#pragma unroll
    for (int ni = 0; ni < 4; ++ni) {
      int gg = wn * 4 + ni;
      bf[ni] = *(const long*)&pb[cur][(gg >> 1) * 1024 + (gg & 1) * 512 + fbase];
    }
#pragma unroll
    for (int mi = 0; mi < 4; ++mi)
#pragma unroll
      for (int ni = 0; ni < 4; ++ni)
        acc[mi][ni] = __builtin_amdgcn_mfma_f32_16x16x32_fp8_fp8(
            af[mi], bf[ni], acc[mi][ni], 0, 0, 0);
    cur = cur == 2 ? 0 : cur + 1;
    nxt = nxt == 2 ? 0 : nxt + 1;
  }

  u16* dst = part + (long)ks * 2097152;
#pragma unroll
  for (int mi = 0; mi < 4; ++mi) {
#pragma unroll
    for (int ni = 0; ni < 4; ++ni) {
      int n = bn + wn * 64 + ni * 16 + r16;
      int m0 = bm + wm * 64 + mi * 16 + quad * 4;
      f4v vv = acc[mi][ni];
#pragma unroll
      for (int r2 = 0; r2 < 4; ++r2)
        dst[(long)(m0 + r2) * 512 + n] = f2bf(vv[r2] * 0.00390625f);
    }
  }
}

// ---------------- bf16 NT GEMM (FINAL: d_out = wo.out_t^T + bo + x) -------
template <int MODE, int BM, int BN>
__global__ __launch_bounds__(256) void gemm_nt(
    const u16* __restrict__ Ag, long sA, const u16* __restrict__ Btg, long sB,
    void* __restrict__ Cg, long sC, int nx, int nyg, int K, long lda, long ldb,
    int N, const float* __restrict__ b0, const float* __restrict__ resid,
    long sR, float scale) {
  constexpr int MI = BM / 32, NI = BN / 32;
  constexpr int AGW = BM / 64, BGW = BN / 64;
  constexpr int NLD = AGW + BGW;
  __shared__ __align__(16) u16 lds_a[3][BM * 32];
  __shared__ __align__(16) u16 lds_b[3][BN * 32];
  const int t = threadIdx.x;
  const int lane = t & 63, wv = t >> 6;
  const int wm = wv >> 1, wn = wv & 1;

  int lin = blockIdx.x;
  int xcd = lin & 7, s = lin >> 3;
  int bn_i = s % nx, t2 = s / nx;
  int bm_i = (t2 % nyg) * 8 + xcd;
  int bz = t2 / nyg;

  const u16* A = Ag + (long)bz * sA;
  const u16* Bt = Btg + (long)bz * sB;
  long c_off = (long)bz * sC;
  const int bm = bm_i * BM, bn = bn_i * BN;

  const u16* aP[AGW];
  const u16* bP[BGW];
#pragma unroll
  for (int j = 0; j < AGW; ++j)
    aP[j] = A + (long)(bm + (wv + j * 4) * 16 + (lane & 15)) * lda +
            (lane >> 4) * 8;
#pragma unroll
  for (int j = 0; j < BGW; ++j)
    bP[j] = Bt + (long)(bn + (wv + j * 4) * 16 + (lane & 15)) * ldb +
            (lane >> 4) * 8;

  auto issue = [&](int buf) {
#pragma unroll
    for (int j = 0; j < AGW; ++j) {
      gload16(aP[j], &lds_a[buf][(wv + j * 4) * 512 + lane * 8]);
      aP[j] += 32;
    }
#pragma unroll
    for (int j = 0; j < BGW; ++j) {
      gload16(bP[j], &lds_b[buf][(wv + j * 4) * 512 + lane * 8]);
      bP[j] += 32;
    }
  };

  f4v acc[MI][NI];
#pragma unroll
  for (int i = 0; i < MI; ++i)
#pragma unroll
    for (int j = 0; j < NI; ++j) acc[i][j] = (f4v){0.f, 0.f, 0.f, 0.f};

  const int NIT = K / 32;
  issue(0);
  issue(1);
  int cur = 0, nxt = 2;
  for (int it = 0; it < NIT; ++it) {
    if (it < NIT - 1)
      asm volatile("s_waitcnt vmcnt(%0)" ::"n"(NLD) : "memory");
    else
      asm volatile("s_waitcnt vmcnt(0)" ::: "memory");
    asm volatile("s_barrier" ::: "memory");
    if (it + 2 < NIT) issue(nxt);

    s8v af[MI], bfr[NI];
#pragma unroll
    for (int mi = 0; mi < MI; ++mi)
      af[mi] = *(const s8v*)&lds_a[cur][((wm * MI + mi) * 64 + lane) * 8];
#pragma unroll
    for (int ni = 0; ni < NI; ++ni)
      bfr[ni] = *(const s8v*)&lds_b[cur][((wn * NI + ni) * 64 + lane) * 8];
#pragma unroll
    for (int mi = 0; mi < MI; ++mi)
#pragma unroll
      for (int ni = 0; ni < NI; ++ni)
        acc[mi][ni] = __builtin_amdgcn_mfma_f32_16x16x32_bf16(
            af[mi], bfr[ni], acc[mi][ni], 0, 0, 0);
    cur = cur == 2 ? 0 : cur + 1;
    nxt = nxt == 2 ? 0 : nxt + 1;
  }

  const int quad = lane >> 4, col = lane & 15;
#pragma unroll
  for (int mi = 0; mi < MI; ++mi) {
#pragma unroll
    for (int ni = 0; ni < NI; ++ni) {
      int n = bn + wn * (BN / 2) + ni * 16 + col;
      int m0 = bm + wm * (BM / 2) + mi * 16 + quad * 4;
      f4v vv = acc[mi][ni];
#pragma unroll
      for (int r2 = 0; r2 < 4; ++r2) {
        int m = m0 + r2;
        float val = vv[r2];
        if constexpr (MODE == MODE_SCALE) val *= scale;
        if constexpr (MODE == MODE_FINAL) {
          val += b0[m] + resid[(long)bz * sR + (long)m * N + n];
          ((float*)Cg)[c_off + (long)m * N + n] = val;
        } else {
          ((u16*)Cg)[c_off + (long)m * N + n] = f2bf(val);
        }
      }
    }
  }
  (void)scale; (void)resid;
}

extern "C" void kernel_launch(void* const* d_in, const int* in_sizes, int n_in,
                              void* d_out, int out_size, void* d_ws,
                              size_t ws_size, hipStream_t stream) {
  const float* x = (const float*)d_in[0];
  const float* gamma = (const float*)d_in[1];
  const float* beta = (const float*)d_in[2];
  const float* wq = (const float*)d_in[3];
  const float* bq = (const float*)d_in[4];
  const float* wk = (const float*)d_in[5];
  const float* bk = (const float*)d_in[6];
  const float* wv = (const float*)d_in[7];
  const float* bv = (const float*)d_in[8];
  const float* wo = (const float*)d_in[9];
  const float* bo = (const float*)d_in[10];

  u8* wsb = (u8*)d_ws;
  u16* hnt = (u16*)wsb;                 // 8MiB: hn^t bf16; later out_t
  u8* q8 = wsb + 8388608;               // 4MiB fp8 [2][4096][512]
  u8* k8 = wsb + 12582912;              // 4MiB
  u8* v8 = wsb + 16777216;              // 4MiB fp8 [2][512][4096]
  u8* P8 = wsb + 20971520;              // 16MiB per-batch P fp8
  u16* S = (u16*)(wsb + 37748736);      // 32MiB per-batch S bf16
  u16* parts = (u16*)(wsb + 71303168);  // 16MiB split-K4 partials
  u16* wqb = (u16*)(wsb + 88080384);    // 2MiB: 4 weights bf16
  u16* wob = wqb + 786432;
  float2* part = (float2*)(wsb + 102760448);
  float2* AB = (float2*)(wsb + 102764544);

  w2bf<<<dim3(256, 4), 256, 0, stream>>>(wq, wk, wv, wo, wqb);
  gn_stats<<<512, 256, 0, stream>>>(x, part);
  gn_ab<<<4, 256, 0, stream>>>(part, gamma, beta, AB);
  gn_apply_t<<<dim3(128, 16, 2), 256, 0, stream>>>(x, AB, hnt);

  // fused q/k/v (all fp8): 512 blocks
  gemm_qkv3<<<512, 256, 0, stream>>>(hnt, wqb, q8, k8, v8, bq, bk, bv);

  for (int b = 0; b < 2; ++b) {
    // S = scale * q8 k8^T (fp8 MFMA): 1024 blocks
    gemm_sc8<<<1024, 256, 0, stream>>>(q8 + (long)b * 2097152,
                                       k8 + (long)b * 2097152, S);
    // softmax -> P fp8 (x256)
    softmax_rows<<<4096, 256, 0, stream>>>(S, P8);
    // PV fp8 split-K4: 512 blocks
    gemm_pv8<<<512, 256, 0, stream>>>(P8, v8 + (long)b * 2097152, parts);
    // out_t[b] = sum of 4 partials
    reduce_pv4<<<1024, 256, 0, stream>>>(parts, hnt + (long)b * 2097152);
  }

  // d_out = wo . out_t^T + bo + x: 64x128, nx=32, nyg=1, nz=2 -> 512 blocks
  gemm_nt<MODE_FINAL, 64, 128><<<512, 256, 0, stream>>>(
      wob, 0, hnt, 2097152, d_out, 2097152, 32, 1, 512, 512, 512, 4096, bo,
      x, 2097152, 0.f);

  (void)in_sizes; (void)n_in; (void)out_size; (void)ws_size;
}

// Round 10
// 250.507 us; speedup vs baseline: 1.2963x; 1.0790x over previous
//
#include <hip/hip_runtime.h>

typedef unsigned short u16;
typedef unsigned char u8;
typedef __attribute__((ext_vector_type(8))) short s8v;
typedef __attribute__((ext_vector_type(4))) float f4v;

enum { MODE_SCALE = 2, MODE_FINAL = 3 };

__device__ __forceinline__ u16 f2bf(float f) {
  unsigned u = __builtin_bit_cast(unsigned, f);
  u += 0x7fffu + ((u >> 16) & 1u);
  return (u16)(u >> 16);
}
__device__ __forceinline__ float bf2f(u16 h) {
  unsigned u = ((unsigned)h) << 16;
  return __builtin_bit_cast(float, u);
}
__device__ __forceinline__ void gload16(const void* g, void* l) {
  __builtin_amdgcn_global_load_lds(
      (const __attribute__((address_space(1))) unsigned int*)g,
      (__attribute__((address_space(3))) unsigned int*)l, 16, 0, 0);
}
__device__ __forceinline__ unsigned pk4fp8(float a, float b, float c, float d) {
  int lo = __builtin_amdgcn_cvt_pk_fp8_f32(a, b, 0, false);
  return (unsigned)__builtin_amdgcn_cvt_pk_fp8_f32(c, d, lo, true);
}
__device__ __forceinline__ u8 f2fp8(float a) {
  return (u8)(__builtin_amdgcn_cvt_pk_fp8_f32(a, a, 0, false) & 0xff);
}

// ---------------- weight fp32 -> bf16 ----------------
__global__ __launch_bounds__(256) void w2bf(const float* __restrict__ w0,
                                            const float* __restrict__ w1,
                                            const float* __restrict__ w2,
                                            const float* __restrict__ w3,
                                            u16* __restrict__ out) {
  int which = blockIdx.y;
  const float* w = which == 0 ? w0 : which == 1 ? w1 : which == 2 ? w2 : w3;
  int i = (blockIdx.x * 256 + threadIdx.x) * 4;
  float4 f = *(const float4*)(w + i);
  u16* o = out + (long)which * 262144 + i;
  ushort4 r;
  r.x = f2bf(f.x); r.y = f2bf(f.y); r.z = f2bf(f.z); r.w = f2bf(f.w);
  *(ushort4*)o = r;
}

// ---------------- groupnorm: partial stats ----------------
__global__ __launch_bounds__(256) void gn_stats(const float* __restrict__ x,
                                                float2* __restrict__ part) {
  const int bid = blockIdx.x;
  const float4* p4 = (const float4*)(x + (long)bid * 8192);
  float s = 0.f, q = 0.f;
  int t = threadIdx.x;
#pragma unroll
  for (int j = 0; j < 8; ++j) {
    float4 f = p4[t + 256 * j];
    s += f.x + f.y + f.z + f.w;
    q += f.x * f.x + f.y * f.y + f.z * f.z + f.w * f.w;
  }
#pragma unroll
  for (int o = 32; o; o >>= 1) {
    s += __shfl_xor(s, o, 64);
    q += __shfl_xor(q, o, 64);
  }
  __shared__ float rs[4], rq[4];
  int lane = t & 63, wv = t >> 6;
  if (lane == 0) { rs[wv] = s; rq[wv] = q; }
  __syncthreads();
  if (t == 0)
    part[bid] = make_float2(rs[0] + rs[1] + rs[2] + rs[3],
                            rq[0] + rq[1] + rq[2] + rq[3]);
}

// ---------------- groupnorm: per-channel scale/shift ----------------
__global__ __launch_bounds__(256) void gn_ab(const float2* __restrict__ part,
                                             const float* __restrict__ gamma,
                                             const float* __restrict__ beta,
                                             float2* __restrict__ AB) {
  int idx = blockIdx.x * 256 + threadIdx.x;
  int g = idx >> 4;
  float s = 0.f, q = 0.f;
#pragma unroll
  for (int j = 0; j < 8; ++j) {
    float2 pp = part[g * 8 + j];
    s += pp.x; q += pp.y;
  }
  float mean = s * (1.0f / 65536.0f);
  float var = q * (1.0f / 65536.0f) - mean * mean;
  int c = idx & 511;
  float a = gamma[c] * rsqrtf(var + 1e-6f);
  AB[idx] = make_float2(a, beta[c] - mean * a);
}

// ---------------- apply groupnorm + transpose ----------------
__global__ __launch_bounds__(256) void gn_apply_t(const float* __restrict__ x,
                                                  const float2* __restrict__ AB,
                                                  u16* __restrict__ hnt) {
  int p0 = blockIdx.x * 32, c0 = blockIdx.y * 32, b = blockIdx.z;
  __shared__ float tile[32][33];
  int t = threadIdx.x;
  const float* xb = x + (long)b * 2097152;
#pragma unroll
  for (int j = 0; j < 4; ++j) {
    int lc = (t >> 5) + j * 8, lp = t & 31;
    tile[lc][lp] = xb[(long)(c0 + lc) * 4096 + p0 + lp];
  }
  __syncthreads();
#pragma unroll
  for (int j = 0; j < 4; ++j) {
    int lp = (t >> 5) + j * 8, lc = t & 31;
    float2 ab = AB[b * 512 + c0 + lc];
    float val = tile[lc][lp] * ab.x + ab.y;
    hnt[(long)b * 2097152 + (long)(p0 + lp) * 512 + c0 + lc] = f2bf(val);
  }
}

// ------- softmax: bf16 S row -> fp8 P row scaled by 256 (both batches) ----
__global__ __launch_bounds__(256) void softmax_rows(const u16* __restrict__ S,
                                                    u8* __restrict__ P) {
  const u16* p = S + (long)blockIdx.x * 4096;
  const int t = threadIdx.x;
  s8v h0 = ((const s8v*)p)[t * 2];
  s8v h1 = ((const s8v*)p)[t * 2 + 1];
  float v[16];
#pragma unroll
  for (int j = 0; j < 8; ++j) {
    v[j] = bf2f((u16)h0[j]);
    v[8 + j] = bf2f((u16)h1[j]);
  }
  float mx = v[0];
#pragma unroll
  for (int j = 1; j < 16; ++j) mx = fmaxf(mx, v[j]);
#pragma unroll
  for (int o = 32; o; o >>= 1) mx = fmaxf(mx, __shfl_xor(mx, o, 64));
  __shared__ float red[4], red2[4];
  int lane = t & 63, wv = t >> 6;
  if (lane == 0) red[wv] = mx;
  __syncthreads();
  mx = fmaxf(fmaxf(red[0], red[1]), fmaxf(red[2], red[3]));
  float s = 0.f;
#pragma unroll
  for (int j = 0; j < 16; ++j) {
    v[j] = __expf(v[j] - mx);
    s += v[j];
  }
#pragma unroll
  for (int o = 32; o; o >>= 1) s += __shfl_xor(s, o, 64);
  if (lane == 0) red2[wv] = s;
  __syncthreads();
  s = red2[0] + red2[1] + red2[2] + red2[3];
  float invs = 256.0f / s;  // x256 keeps diffuse P out of e4m3 underflow
  uint4 o4;
  o4.x = pk4fp8(v[0] * invs, v[1] * invs, v[2] * invs, v[3] * invs);
  o4.y = pk4fp8(v[4] * invs, v[5] * invs, v[6] * invs, v[7] * invs);
  o4.z = pk4fp8(v[8] * invs, v[9] * invs, v[10] * invs, v[11] * invs);
  o4.w = pk4fp8(v[12] * invs, v[13] * invs, v[14] * invs, v[15] * invs);
  *(uint4*)(P + (long)blockIdx.x * 4096 + t * 16) = o4;
}

// ------- split-K4 reduce -> out_t (bf16), both batches --------------------
// parts layout [2][4][4096][512]; out (hnt) [2][4096][512].
__global__ __launch_bounds__(256) void reduce_pv4(const u16* __restrict__ parts,
                                                  u16* __restrict__ out) {
  long i = ((long)blockIdx.x * 256 + threadIdx.x) * 8;  // [0, 4194304)
  long b = i >> 21, off = i & 2097151;
  const u16* base = parts + b * 8388608 + off;
  s8v a = *(const s8v*)(base);
  s8v bb = *(const s8v*)(base + 2097152);
  s8v c = *(const s8v*)(base + 4194304);
  s8v d = *(const s8v*)(base + 6291456);
  s8v o;
#pragma unroll
  for (int j = 0; j < 8; ++j)
    o[j] = (short)f2bf(bf2f((u16)a[j]) + bf2f((u16)bb[j]) + bf2f((u16)c[j]) +
                       bf2f((u16)d[j]));
  *(s8v*)(out + i) = o;
}

// ---------------- fused QKV GEMM: q,k,v all written fp8 -------------------
__global__ __launch_bounds__(256) void gemm_qkv3(
    const u16* __restrict__ hnt, const u16* __restrict__ wqb,
    u8* __restrict__ q8, u8* __restrict__ k8, u8* __restrict__ v8,
    const float* __restrict__ bq, const float* __restrict__ bk,
    const float* __restrict__ bv) {
  constexpr int MI = 4, NI = 2, AGW = 2, NLD = 5;
  __shared__ __align__(16) u16 la[3][4096];
  __shared__ __align__(16) u16 lb[3][3][2048];
  const int t = threadIdx.x;
  const int lane = t & 63, wv = t >> 6;
  const int wm = wv >> 1, wn = wv & 1;

  int lin = blockIdx.x;
  int xcd = lin & 7, s = lin >> 3;
  int bn_i = s % 8, t2 = s / 8;
  int bm_i = (t2 % 4) * 8 + xcd;
  int bb = t2 / 4;
  const int bm = bm_i * 128, bn = bn_i * 64;

  const u16* A = hnt + (long)bb * 2097152;
  const u16* aP[AGW];
#pragma unroll
  for (int j = 0; j < AGW; ++j)
    aP[j] = A + (long)(bm + (wv + j * 4) * 16 + (lane & 15)) * 512 +
            (lane >> 4) * 8;
  const u16* bP[3];
#pragma unroll
  for (int w = 0; w < 3; ++w)
    bP[w] = wqb + (long)w * 262144 +
            (long)(bn + wv * 16 + (lane & 15)) * 512 + (lane >> 4) * 8;

  auto issue = [&](int buf) {
#pragma unroll
    for (int j = 0; j < AGW; ++j) {
      gload16(aP[j], &la[buf][(wv + j * 4) * 512 + lane * 8]);
      aP[j] += 32;
    }
#pragma unroll
    for (int w = 0; w < 3; ++w) {
      gload16(bP[w], &lb[buf][w][wv * 512 + lane * 8]);
      bP[w] += 32;
    }
  };

  f4v acc[3][MI][NI];
#pragma unroll
  for (int w = 0; w < 3; ++w)
#pragma unroll
    for (int i = 0; i < MI; ++i)
#pragma unroll
      for (int j = 0; j < NI; ++j) acc[w][i][j] = (f4v){0.f, 0.f, 0.f, 0.f};

  issue(0);
  issue(1);
  int cur = 0, nxt = 2;
  for (int it = 0; it < 16; ++it) {
    if (it < 15)
      asm volatile("s_waitcnt vmcnt(%0)" ::"n"(NLD) : "memory");
    else
      asm volatile("s_waitcnt vmcnt(0)" ::: "memory");
    asm volatile("s_barrier" ::: "memory");
    if (it + 2 < 16) issue(nxt);

    s8v af[MI], bfr[3][NI];
#pragma unroll
    for (int mi = 0; mi < MI; ++mi)
      af[mi] = *(const s8v*)&la[cur][((wm * MI + mi) * 64 + lane) * 8];
#pragma unroll
    for (int w = 0; w < 3; ++w)
#pragma unroll
      for (int ni = 0; ni < NI; ++ni)
        bfr[w][ni] =
            *(const s8v*)&lb[cur][w][((wn * NI + ni) * 64 + lane) * 8];
#pragma unroll
    for (int w = 0; w < 3; ++w)
#pragma unroll
      for (int mi = 0; mi < MI; ++mi)
#pragma unroll
        for (int ni = 0; ni < NI; ++ni)
          acc[w][mi][ni] = __builtin_amdgcn_mfma_f32_16x16x32_bf16(
              af[mi], bfr[w][ni], acc[w][mi][ni], 0, 0, 0);
    cur = cur == 2 ? 0 : cur + 1;
    nxt = nxt == 2 ? 0 : nxt + 1;
  }

  const int quad = lane >> 4, col = lane & 15;
#pragma unroll
  for (int w = 0; w < 3; ++w) {
    const float* bias = w == 0 ? bq : w == 1 ? bk : bv;
    u8* dst = w == 0 ? q8 : k8;
#pragma unroll
    for (int mi = 0; mi < MI; ++mi) {
#pragma unroll
      for (int ni = 0; ni < NI; ++ni) {
        int n = bn + wn * 32 + ni * 16 + col;
        int m0 = bm + wm * 64 + mi * 16 + quad * 4;
        f4v vv = acc[w][mi][ni];
        float bsv = bias[n];
        if (w == 2) {
          *(unsigned*)&v8[(long)bb * 2097152 + (long)n * 4096 + m0] =
              pk4fp8(vv[0] + bsv, vv[1] + bsv, vv[2] + bsv, vv[3] + bsv);
        } else {
#pragma unroll
          for (int r2 = 0; r2 < 4; ++r2)
            dst[(long)bb * 2097152 + (long)(m0 + r2) * 512 + n] =
                f2fp8(vv[r2] + bsv);
        }
      }
    }
  }
}

// ---------------- fp8 scores GEMM, both batches: 2048 blocks --------------
__global__ __launch_bounds__(256) void gemm_sc8(const u8* __restrict__ q8,
                                                const u8* __restrict__ k8,
                                                u16* __restrict__ S) {
  __shared__ __align__(16) u8 pa[3][4096];
  __shared__ __align__(16) u8 pb[3][4096];
  const int t = threadIdx.x;
  const int lane = t & 63, wv = t >> 6;
  const int wm = wv >> 1, wn = wv & 1;

  int lin = blockIdx.x;
  int xcd = lin & 7, s = lin >> 3;
  int bn_i = s & 31, t2 = s >> 5;  // t2 in [0,8)
  int bm_i = (t2 & 3) * 8 + xcd;
  int b = t2 >> 2;
  const int bm = bm_i * 128, bn = bn_i * 128;

  const u8* qb = q8 + (long)b * 2097152;
  const u8* kb = k8 + (long)b * 2097152;
  const int srow = (lane & 15) + 16 * (lane >> 5);
  const int skof = ((lane >> 4) & 1) * 16;
  const u8* aP = qb + (long)(bm + wv * 32 + srow) * 512 + skof;
  const u8* bP = kb + (long)(bn + wv * 32 + srow) * 512 + skof;

  auto issue = [&](int buf) {
    gload16(aP, &pa[buf][t * 16]);
    aP += 32;
    gload16(bP, &pb[buf][t * 16]);
    bP += 32;
  };

  f4v acc[4][4];
#pragma unroll
  for (int i = 0; i < 4; ++i)
#pragma unroll
    for (int j = 0; j < 4; ++j) acc[i][j] = (f4v){0.f, 0.f, 0.f, 0.f};

  issue(0);
  issue(1);
  int cur = 0, nxt = 2;
  const int quad = lane >> 4, qh = quad >> 1, ql = quad & 1, r16 = lane & 15;
  const int fbase = qh * 256 + r16 * 16 + ql * 8;
  for (int it = 0; it < 16; ++it) {
    if (it < 15)
      asm volatile("s_waitcnt vmcnt(2)" ::: "memory");
    else
      asm volatile("s_waitcnt vmcnt(0)" ::: "memory");
    asm volatile("s_barrier" ::: "memory");
    if (it + 2 < 16) issue(nxt);

    long af[4], bf[4];
#pragma unroll
    for (int mi = 0; mi < 4; ++mi) {
      int gg = wm * 4 + mi;
      af[mi] = *(const long*)&pa[cur][(gg >> 1) * 1024 + (gg & 1) * 512 + fbase];
    }
#pragma unroll
    for (int ni = 0; ni < 4; ++ni) {
      int gg = wn * 4 + ni;
      bf[ni] = *(const long*)&pb[cur][(gg >> 1) * 1024 + (gg & 1) * 512 + fbase];
    }
#pragma unroll
    for (int mi = 0; mi < 4; ++mi)
#pragma unroll
      for (int ni = 0; ni < 4; ++ni)
        acc[mi][ni] = __builtin_amdgcn_mfma_f32_16x16x32_fp8_fp8(
            af[mi], bf[ni], acc[mi][ni], 0, 0, 0);
    cur = cur == 2 ? 0 : cur + 1;
    nxt = nxt == 2 ? 0 : nxt + 1;
  }

  u16* Sb = S + (long)b * 16777216;
#pragma unroll
  for (int mi = 0; mi < 4; ++mi) {
#pragma unroll
    for (int ni = 0; ni < 4; ++ni) {
      int n = bn + wn * 64 + ni * 16 + r16;
      int m0 = bm + wm * 64 + mi * 16 + quad * 4;
      f4v vv = acc[mi][ni];
#pragma unroll
      for (int r2 = 0; r2 < 4; ++r2)
        Sb[(long)(m0 + r2) * 4096 + n] = f2bf(vv[r2] * 0.044194173824159216f);
    }
  }
}

// ---------------- fp8 PV GEMM, both batches: 1024 blocks ------------------
__global__ __launch_bounds__(256) void gemm_pv8(const u8* __restrict__ P8,
                                                const u8* __restrict__ v8,
                                                u16* __restrict__ parts) {
  __shared__ __align__(16) u8 pa[3][4096];
  __shared__ __align__(16) u8 pb[3][4096];
  const int t = threadIdx.x;
  const int lane = t & 63, wv = t >> 6;
  const int wm = wv >> 1, wn = wv & 1;

  int lin = blockIdx.x;
  int xcd = lin & 7, s = lin >> 3;  // s in [0,128)
  int bn_i = s & 3, t2 = s >> 2;    // t2 in [0,32)
  int bm_i = (t2 & 3) * 8 + xcd;
  int r = t2 >> 2;                  // [0,8)
  int ks = r & 3, b = r >> 2;
  const int bm = bm_i * 128, bn = bn_i * 128;

  const u8* P = P8 + (long)b * 16777216;
  const u8* V = v8 + (long)b * 2097152;
  const int srow = (lane & 15) + 16 * (lane >> 5);
  const int skof = ((lane >> 4) & 1) * 16;
  const u8* aP = P + (long)(bm + wv * 32 + srow) * 4096 + ks * 1024 + skof;
  const u8* bP = V + (long)(bn + wv * 32 + srow) * 4096 + ks * 1024 + skof;

  auto issue = [&](int buf) {
    gload16(aP, &pa[buf][t * 16]);
    aP += 32;
    gload16(bP, &pb[buf][t * 16]);
    bP += 32;
  };

  f4v acc[4][4];
#pragma unroll
  for (int i = 0; i < 4; ++i)
#pragma unroll
    for (int j = 0; j < 4; ++j) acc[i][j] = (f4v){0.f, 0.f, 0.f, 0.f};

  issue(0);
  issue(1);
  int cur = 0, nxt = 2;
  const int quad = lane >> 4, qh = quad >> 1, ql = quad & 1, r16 = lane & 15;
  const int fbase = qh * 256 + r16 * 16 + ql * 8;
  for (int it = 0; it < 32; ++it) {
    if (it < 31)
      asm volatile("s_waitcnt vmcnt(2)" ::: "memory");
    else
      asm volatile("s_waitcnt vmcnt(0)" ::: "memory");
    asm volatile("s_barrier" ::: "memory");
    if (it + 2 < 32) issue(nxt);

    long af[4], bf[4];
#pragma unroll
    for (int mi = 0; mi < 4; ++mi) {
      int gg = wm * 4 + mi;
      af[mi] = *(const long*)&pa[cur][(gg >> 1) * 1024 + (gg & 1) * 512 + fbase];
    }
#pragma unroll
    for (int ni = 0; ni < 4; ++ni) {
      int gg = wn * 4 + ni;
      bf[ni] = *(const long*)&pb[cur][(gg >> 1) * 1024 + (gg & 1) * 512 + fbase];
    }
#pragma unroll
    for (int mi = 0; mi < 4; ++mi)
#pragma unroll
      for (int ni = 0; ni < 4; ++ni)
        acc[mi][ni] = __builtin_amdgcn_mfma_f32_16x16x32_fp8_fp8(
            af[mi], bf[ni], acc[mi][ni], 0, 0, 0);
    cur = cur == 2 ? 0 : cur + 1;
    nxt = nxt == 2 ? 0 : nxt + 1;
  }

  u16* dst = parts + (long)b * 8388608 + (long)ks * 2097152;
#pragma unroll
  for (int mi = 0; mi < 4; ++mi) {
#pragma unroll
    for (int ni = 0; ni < 4; ++ni) {
      int n = bn + wn * 64 + ni * 16 + r16;
      int m0 = bm + wm * 64 + mi * 16 + quad * 4;
      f4v vv = acc[mi][ni];
#pragma unroll
      for (int r2 = 0; r2 < 4; ++r2)
        dst[(long)(m0 + r2) * 512 + n] = f2bf(vv[r2] * 0.00390625f);
    }
  }
}

// ---------------- bf16 NT GEMM (FINAL) ------------------------------------
template <int MODE, int BM, int BN>
__global__ __launch_bounds__(256) void gemm_nt(
    const u16* __restrict__ Ag, long sA, const u16* __restrict__ Btg, long sB,
    void* __restrict__ Cg, long sC, int nx, int nyg, int K, long lda, long ldb,
    int N, const float* __restrict__ b0, const float* __restrict__ resid,
    long sR, float scale) {
  constexpr int MI = BM / 32, NI = BN / 32;
  constexpr int AGW = BM / 64, BGW = BN / 64;
  constexpr int NLD = AGW + BGW;
  __shared__ __align__(16) u16 lds_a[3][BM * 32];
  __shared__ __align__(16) u16 lds_b[3][BN * 32];
  const int t = threadIdx.x;
  const int lane = t & 63, wv = t >> 6;
  const int wm = wv >> 1, wn = wv & 1;

  int lin = blockIdx.x;
  int xcd = lin & 7, s = lin >> 3;
  int bn_i = s % nx, t2 = s / nx;
  int bm_i = (t2 % nyg) * 8 + xcd;
  int bz = t2 / nyg;

  const u16* A = Ag + (long)bz * sA;
  const u16* Bt = Btg + (long)bz * sB;
  long c_off = (long)bz * sC;
  const int bm = bm_i * BM, bn = bn_i * BN;

  const u16* aP[AGW];
  const u16* bP[BGW];
#pragma unroll
  for (int j = 0; j < AGW; ++j)
    aP[j] = A + (long)(bm + (wv + j * 4) * 16 + (lane & 15)) * lda +
            (lane >> 4) * 8;
#pragma unroll
  for (int j = 0; j < BGW; ++j)
    bP[j] = Bt + (long)(bn + (wv + j * 4) * 16 + (lane & 15)) * ldb +
            (lane >> 4) * 8;

  auto issue = [&](int buf) {
#pragma unroll
    for (int j = 0; j < AGW; ++j) {
      gload16(aP[j], &lds_a[buf][(wv + j * 4) * 512 + lane * 8]);
      aP[j] += 32;
    }
#pragma unroll
    for (int j = 0; j < BGW; ++j) {
      gload16(bP[j], &lds_b[buf][(wv + j * 4) * 512 + lane * 8]);
      bP[j] += 32;
    }
  };

  f4v acc[MI][NI];
#pragma unroll
  for (int i = 0; i < MI; ++i)
#pragma unroll
    for (int j = 0; j < NI; ++j) acc[i][j] = (f4v){0.f, 0.f, 0.f, 0.f};

  const int NIT = K / 32;
  issue(0);
  issue(1);
  int cur = 0, nxt = 2;
  for (int it = 0; it < NIT; ++it) {
    if (it < NIT - 1)
      asm volatile("s_waitcnt vmcnt(%0)" ::"n"(NLD) : "memory");
    else
      asm volatile("s_waitcnt vmcnt(0)" ::: "memory");
    asm volatile("s_barrier" ::: "memory");
    if (it + 2 < NIT) issue(nxt);

    s8v af[MI], bfr[NI];
#pragma unroll
    for (int mi = 0; mi < MI; ++mi)
      af[mi] = *(const s8v*)&lds_a[cur][((wm * MI + mi) * 64 + lane) * 8];
#pragma unroll
    for (int ni = 0; ni < NI; ++ni)
      bfr[ni] = *(const s8v*)&lds_b[cur][((wn * NI + ni) * 64 + lane) * 8];
#pragma unroll
    for (int mi = 0; mi < MI; ++mi)
#pragma unroll
      for (int ni = 0; ni < NI; ++ni)
        acc[mi][ni] = __builtin_amdgcn_mfma_f32_16x16x32_bf16(
            af[mi], bfr[ni], acc[mi][ni], 0, 0, 0);
    cur = cur == 2 ? 0 : cur + 1;
    nxt = nxt == 2 ? 0 : nxt + 1;
  }

  const int quad = lane >> 4, col = lane & 15;
#pragma unroll
  for (int mi = 0; mi < MI; ++mi) {
#pragma unroll
    for (int ni = 0; ni < NI; ++ni) {
      int n = bn + wn * (BN / 2) + ni * 16 + col;
      int m0 = bm + wm * (BM / 2) + mi * 16 + quad * 4;
      f4v vv = acc[mi][ni];
#pragma unroll
      for (int r2 = 0; r2 < 4; ++r2) {
        int m = m0 + r2;
        float val = vv[r2];
        if constexpr (MODE == MODE_SCALE) val *= scale;
        if constexpr (MODE == MODE_FINAL) {
          val += b0[m] + resid[(long)bz * sR + (long)m * N + n];
          ((float*)Cg)[c_off + (long)m * N + n] = val;
        } else {
          ((u16*)Cg)[c_off + (long)m * N + n] = f2bf(val);
        }
      }
    }
  }
  (void)scale; (void)resid;
}

extern "C" void kernel_launch(void* const* d_in, const int* in_sizes, int n_in,
                              void* d_out, int out_size, void* d_ws,
                              size_t ws_size, hipStream_t stream) {
  const float* x = (const float*)d_in[0];
  const float* gamma = (const float*)d_in[1];
  const float* beta = (const float*)d_in[2];
  const float* wq = (const float*)d_in[3];
  const float* bq = (const float*)d_in[4];
  const float* wk = (const float*)d_in[5];
  const float* bk = (const float*)d_in[6];
  const float* wv = (const float*)d_in[7];
  const float* bv = (const float*)d_in[8];
  const float* wo = (const float*)d_in[9];
  const float* bo = (const float*)d_in[10];

  // ws_size = 256 MiB (observed: harness poison fill writes 262144 KB).
  u8* wsb = (u8*)d_ws;
  u16* hnt = (u16*)wsb;                  // 8M: hn^t bf16; later out_t
  u8* q8 = wsb + 8388608;                // 4M fp8 [2][4096][512]
  u8* k8 = wsb + 12582912;               // 4M
  u8* v8 = wsb + 16777216;               // 4M fp8 [2][512][4096]
  u16* wqb = (u16*)(wsb + 20971520);     // 2M: 4 weights bf16
  u16* wob = wqb + 786432;
  float2* part = (float2*)(wsb + 23068672);
  float2* AB = (float2*)(wsb + 23072768);
  u16* S = (u16*)(wsb + 25165824);       // 64M: [2][4096][4096] bf16
  u8* P8 = wsb + 92274688;               // 32M: [2][4096][4096] fp8
  u16* parts = (u16*)(wsb + 125829120);  // 32M: [2][4][4096][512] bf16

  w2bf<<<dim3(256, 4), 256, 0, stream>>>(wq, wk, wv, wo, wqb);
  gn_stats<<<512, 256, 0, stream>>>(x, part);
  gn_ab<<<4, 256, 0, stream>>>(part, gamma, beta, AB);
  gn_apply_t<<<dim3(128, 16, 2), 256, 0, stream>>>(x, AB, hnt);

  // fused q/k/v (all fp8): 512 blocks
  gemm_qkv3<<<512, 256, 0, stream>>>(hnt, wqb, q8, k8, v8, bq, bk, bv);

  // S = scale * q8 k8^T, both batches: 2048 blocks
  gemm_sc8<<<2048, 256, 0, stream>>>(q8, k8, S);
  // softmax -> P fp8 (x256), both batches
  softmax_rows<<<8192, 256, 0, stream>>>(S, P8);
  // PV fp8 split-K4, both batches: 1024 blocks
  gemm_pv8<<<1024, 256, 0, stream>>>(P8, v8, parts);
  // out_t = sum of 4 partials, both batches
  reduce_pv4<<<2048, 256, 0, stream>>>(parts, hnt);

  // d_out = wo . out_t^T + bo + x: 64x128, nx=32, nyg=1, nz=2 -> 512 blocks
  gemm_nt<MODE_FINAL, 64, 128><<<512, 256, 0, stream>>>(
      wob, 0, hnt, 2097152, d_out, 2097152, 32, 1, 512, 512, 512, 4096, bo,
      x, 2097152, 0.f);

  (void)in_sizes; (void)n_in; (void)out_size; (void)ws_size;
}